// Round 10
// baseline (269.104 us; speedup 1.0000x reference)
//
#include <hip/hip_runtime.h>
#include <hip/hip_fp16.h>

#define NN 50000
#define NE 1000000
#define D  64
#define ED 16
#define CAP 64
#define BN_EPS 1e-5f
#define QSCALE 1048576.0f           // 2^20 fixed-point scale for deterministic agg

// radix partition params (tier-1 path)
#define BSH  7                      // 128 nodes per bucket
#define NBKT 391                    // ceil(50000/128)
#define BCAP 3072                   // per-bucket capacity (mean 2560, > +8 sigma)
#define EPB2 4096                   // edges per partA2 block

typedef _Float16 f16;
typedef _Float16 f16x2 __attribute__((ext_vector_type(2)));

struct alignas(16) SE8  { int v[8]; };        // 4 {src,eid} pairs (fallback path)
struct alignas(16) H16  { unsigned u[8]; };   // 16 halves (one fp16 attr row)
struct alignas(16) F16v { float f[16]; };     // one f32 attr row (fallback)

// =====================  x -> fp16 side copy  =====================
__global__ __launch_bounds__(256) void xhalf_kernel(
    const float* __restrict__ x, __half* __restrict__ xh)
{
    const int i = blockIdx.x * 256 + threadIdx.x;
    if (i >= NN * D / 4) return;
    const float4 a = reinterpret_cast<const float4*>(x)[i];
    ushort4 h;
    h.x = __half_as_ushort(__float2half(a.x));
    h.y = __half_as_ushort(__float2half(a.y));
    h.z = __half_as_ushort(__float2half(a.z));
    h.w = __half_as_ushort(__float2half(a.w));
    reinterpret_cast<ushort4*>(xh)[i] = h;
}

// ==== partA2: radix partition WITH attr payload (src|dst 4B + fp16 attr 32B) ====
__global__ __launch_bounds__(512) void partA2_kernel(
    const int*   __restrict__ ei32,
    const float* __restrict__ ea,
    int*         __restrict__ gcur,    // [NBKT], zeroed
    unsigned*    __restrict__ bse,     // [NBKT*BCAP]  src16|dst16
    __half*      __restrict__ battr)   // [NBKT*BCAP*ED]
{
    __shared__ unsigned       s_se[EPB2];     // 16 KB  (src16|dst16, rank order)
    __shared__ unsigned short s_k[EPB2];      //  8 KB  (block-local edge idx)
    __shared__ int s_cnt[NBKT], s_pref[NBKT], s_cnt2[NBKT], s_gbase[NBKT]; // 6.3 KB

    const int tid = threadIdx.x;
    const long long base = (long long)blockIdx.x * EPB2;
    const int nedge = (int)(((long long)NE - base < EPB2) ? (NE - base) : EPB2);

    const int hi = ei32[2 * (tid & 63) + 1];
    const bool is64 = !__any(hi != 0);

    for (int i = tid; i < NBKT; i += 512) { s_cnt[i] = 0; s_cnt2[i] = 0; }
    __syncthreads();

    int srcv[8], dstv[8];
    #pragma unroll
    for (int i = 0; i < 8; ++i) {
        const int k = i * 512 + tid;
        int s = 0, d = 0;
        if (k < nedge) {
            const long long e = base + k;
            s = is64 ? ei32[2 * e]        : ei32[e];
            d = is64 ? ei32[2 * (NE + e)] : ei32[NE + e];
            atomicAdd(&s_cnt[d >> BSH], 1);
        }
        srcv[i] = s; dstv[i] = d;
    }
    __syncthreads();

    // inclusive Hillis-Steele scan over NBKT entries
    if (tid < NBKT) s_pref[tid] = s_cnt[tid];
    __syncthreads();
    for (int off = 1; off < NBKT; off <<= 1) {
        int v = 0;
        if (tid < NBKT && tid >= off) v = s_pref[tid - off];
        __syncthreads();
        if (tid < NBKT) s_pref[tid] += v;
        __syncthreads();
    }
    if (tid < NBKT) s_gbase[tid] = atomicAdd(&gcur[tid], s_cnt[tid]);
    __syncthreads();

    // rank + stage {se, k}
    #pragma unroll
    for (int i = 0; i < 8; ++i) {
        const int k = i * 512 + tid;
        if (k < nedge) {
            const int d = dstv[i], b = d >> BSH;
            const int r = atomicAdd(&s_cnt2[b], 1);
            const int p = (s_pref[b] - s_cnt[b]) + r;
            s_se[p] = (unsigned)srcv[i] | ((unsigned)d << 16);
            s_k[p]  = (unsigned short)k;
        }
    }
    __syncthreads();

    // flush: run-contiguous payload writes; ea read once per row (L2 window)
    for (int p = tid; p < nedge; p += 512) {
        const unsigned se = s_se[p];
        const int k = s_k[p];
        const int d = (int)(se >> 16), b = d >> BSH;
        const int gpos = s_gbase[b] + (p - (s_pref[b] - s_cnt[b]));
        if (gpos < BCAP) {
            bse[(size_t)b * BCAP + gpos] = se;
            const float4* er = reinterpret_cast<const float4*>(ea + (base + k) * ED);
            float f[16];
            *reinterpret_cast<float4*>(f + 0)  = er[0];
            *reinterpret_cast<float4*>(f + 4)  = er[1];
            *reinterpret_cast<float4*>(f + 8)  = er[2];
            *reinterpret_cast<float4*>(f + 12) = er[3];
            unsigned u[8];
            #pragma unroll
            for (int q = 0; q < 8; ++q) {
                const unsigned lo = __half_as_ushort(__float2half(f[2*q]));
                const unsigned hh = __half_as_ushort(__float2half(f[2*q+1]));
                u[q] = lo | (hh << 16);
            }
            uint4* dst = reinterpret_cast<uint4*>(battr + ((size_t)b * BCAP + gpos) * ED);
            dst[0] = make_uint4(u[0], u[1], u[2], u[3]);
            dst[1] = make_uint4(u[4], u[5], u[6], u[7]);
        }
    }
}

// ==== gather3: per-bucket sequential scan, LDS fixed-point accumulation ====
__global__ __launch_bounds__(256) void gather3_kernel(
    const unsigned* __restrict__ bse,
    const __half*   __restrict__ battr,
    const int*      __restrict__ gcur,
    const __half*   __restrict__ xh,
    const float*    __restrict__ W_edge,
    const float*    __restrict__ b_edge,
    float*          __restrict__ agg)
{
    __shared__ int s_acc[128 * 64];   // 32 KB fixed-point accumulators
    const int tid  = threadIdx.x;
    const int lane = tid & 63;
    const int w    = tid >> 6;
    const int b    = blockIdx.x;

    for (int i = tid; i < 128 * 64; i += 256) s_acc[i] = 0;

    // lane's W_edge row packed to f16x2
    f16x2 wp[8];
    #pragma unroll
    for (int i = 0; i < 8; ++i) {
        const float2 t = reinterpret_cast<const float2*>(W_edge)[lane * 8 + i];
        f16x2 p; p.x = (f16)t.x; p.y = (f16)t.y;
        wp[i] = p;
    }
    const float bo = b_edge[lane];
    __syncthreads();

    const int cnt = __builtin_amdgcn_readfirstlane(min(gcur[b], BCAP));
    const int chunk4 = ((cnt + 15) >> 4) << 2;            // per-wave, multiple of 4
    const int wstart = w * chunk4;
    const int wend   = min(wstart + chunk4, cnt);

    const unsigned* rowse = bse   + (size_t)b * BCAP;
    const __half*   rowat = battr + (size_t)b * BCAP * ED;

    if (wend > wstart) {
        const int G = (wend - wstart + 3) >> 2;

        auto LD_SE = [&](int g) -> uint4 {
            return *reinterpret_cast<const uint4*>(rowse + wstart + g * 4);
        };
        auto LD_GRP = [&](const uint4& s4, int g, H16 at[4], float xv[4],
                          int dl[4], bool lv[4]) {
            #pragma unroll
            for (int j = 0; j < 4; ++j) {
                const int idx = wstart + g * 4 + j;
                const bool lj = idx < wend;               // wave-uniform
                const unsigned sj = (j == 0) ? s4.x : (j == 1) ? s4.y
                                 : (j == 2) ? s4.z : s4.w;
                const unsigned se = lj ? sj : s4.x;       // clamp to group head
                const int src = __builtin_amdgcn_readfirstlane((int)(se & 0xffffu));
                dl[j] = __builtin_amdgcn_readfirstlane((int)((se >> 16) & 127u));
                const int ii = lj ? idx : (wstart + g * 4);
                at[j] = *reinterpret_cast<const H16*>(rowat + (size_t)ii * ED);
                xv[j] = __half2float(xh[(size_t)src * D + lane]);
                lv[j] = lj;
            }
        };
        auto COMP = [&](const H16 at[4], const float xv[4],
                        const int dl[4], const bool lv[4]) {
            #pragma unroll
            for (int j = 0; j < 4; ++j) {
                if (lv[j]) {                              // wave-uniform
                    float d = bo;
                    #pragma unroll
                    for (int k = 0; k < 8; ++k)
                        d = __builtin_amdgcn_fdot2(
                                __builtin_bit_cast(f16x2, at[j].u[k]), wp[k], d, false);
                    const float m = fmaxf(d + xv[j], 0.f);
                    atomicAdd(&s_acc[dl[j] * 64 + lane], __float2int_rn(m * QSCALE));
                }
            }
        };

        H16 atA[4], atB[4];
        float xvA[4], xvB[4];
        int dlA[4], dlB[4];
        bool lvA[4], lvB[4];
        uint4 sB = LD_SE(0);
        LD_GRP(sB, 0, atA, xvA, dlA, lvA);
        if (G > 1) sB = LD_SE(1);

        for (int g = 0; g < G; g += 2) {
            if (g + 1 < G) LD_GRP(sB, g + 1, atB, xvB, dlB, lvB);
            if (g + 2 < G) sB = LD_SE(g + 2);
            COMP(atA, xvA, dlA, lvA);
            if (g + 2 < G) LD_GRP(sB, g + 2, atA, xvA, dlA, lvA);
            if (g + 3 < G) sB = LD_SE(g + 3);
            if (g + 1 < G) COMP(atB, xvB, dlB, lvB);
        }
    }
    __syncthreads();

    const float inv = 1.0f / QSCALE;
    for (int r = w; r < 128; r += 4) {
        const int n = (b << BSH) + r;
        if (n < NN) agg[(size_t)n * D + lane] = (float)s_acc[r * 64 + lane] * inv;
    }
}

// ============== fallback scatter (global atomic slot assignment) =============
__global__ __launch_bounds__(256) void scatter_kernel(
    const int* __restrict__ ei32,
    int*       __restrict__ cursor,
    int2*      __restrict__ padded)
{
    const int e = blockIdx.x * 256 + threadIdx.x;
    const int hi = ei32[2 * (threadIdx.x & 63) + 1];
    const bool is64 = !__any(hi != 0);
    if (e >= NE) return;
    const int src = is64 ? ei32[2 * e]        : ei32[e];
    const int dst = is64 ? ei32[2 * (NE + e)] : ei32[NE + e];
    const int slot = atomicAdd(&cursor[dst], 1);
    if (slot < CAP) padded[(size_t)dst * CAP + slot] = make_int2(src, e);
}

// =============== fallback gather (R8): scalar-pipe f32 attrs ================
template<bool XH>
__global__ __launch_bounds__(256) void gather_kernel(
    const int2*  __restrict__ padded,
    const int*   __restrict__ cursor,
    const float* __restrict__ x,
    const __half* __restrict__ xh,
    const float* __restrict__ ea,
    const float* __restrict__ W_edge,
    const float* __restrict__ b_edge,
    float*       __restrict__ agg)
{
    const int tid  = threadIdx.x;
    const int lane = tid & 63;
    const int n = __builtin_amdgcn_readfirstlane(blockIdx.x * 4 + (tid >> 6));
    if (n >= NN) return;

    float wv[ED];
    #pragma unroll
    for (int i = 0; i < ED / 4; ++i) {
        float4 t = reinterpret_cast<const float4*>(W_edge)[lane * (ED / 4) + i];
        wv[4*i+0] = t.x; wv[4*i+1] = t.y; wv[4*i+2] = t.z; wv[4*i+3] = t.w;
    }
    const float bo = b_edge[lane];

    const int deg = __builtin_amdgcn_readfirstlane(min(cursor[n], CAP));
    const int2* row = padded + (size_t)n * CAP;

    int iacc = 0;
    for (int e0 = 0; e0 < deg; e0 += 4) {
        const SE8 g = *reinterpret_cast<const SE8*>(row + e0);
        const bool l1 = (e0 + 1 < deg), l2 = (e0 + 2 < deg), l3 = (e0 + 3 < deg);
        const int src0 = __builtin_amdgcn_readfirstlane(g.v[0]);
        const int eid0 = __builtin_amdgcn_readfirstlane(g.v[1]);
        const int src1 = __builtin_amdgcn_readfirstlane(l1 ? g.v[2] : g.v[0]);
        const int eid1 = __builtin_amdgcn_readfirstlane(l1 ? g.v[3] : g.v[1]);
        const int src2 = __builtin_amdgcn_readfirstlane(l2 ? g.v[4] : g.v[0]);
        const int eid2 = __builtin_amdgcn_readfirstlane(l2 ? g.v[5] : g.v[1]);
        const int src3 = __builtin_amdgcn_readfirstlane(l3 ? g.v[6] : g.v[0]);
        const int eid3 = __builtin_amdgcn_readfirstlane(l3 ? g.v[7] : g.v[1]);

        const F16v a0 = *reinterpret_cast<const F16v*>(ea + (size_t)eid0 * ED);
        const F16v a1 = *reinterpret_cast<const F16v*>(ea + (size_t)eid1 * ED);
        const F16v a2 = *reinterpret_cast<const F16v*>(ea + (size_t)eid2 * ED);
        const F16v a3 = *reinterpret_cast<const F16v*>(ea + (size_t)eid3 * ED);

        float xv0, xv1, xv2, xv3;
        if (XH) {
            xv0 = __half2float(xh[(size_t)src0 * D + lane]);
            xv1 = __half2float(xh[(size_t)src1 * D + lane]);
            xv2 = __half2float(xh[(size_t)src2 * D + lane]);
            xv3 = __half2float(xh[(size_t)src3 * D + lane]);
        } else {
            xv0 = x[(size_t)src0 * D + lane];
            xv1 = x[(size_t)src1 * D + lane];
            xv2 = x[(size_t)src2 * D + lane];
            xv3 = x[(size_t)src3 * D + lane];
        }

        float d0 = bo, d1 = bo, d2 = bo, d3 = bo;
        #pragma unroll
        for (int k = 0; k < ED; ++k) {
            d0 += a0.f[k] * wv[k];
            d1 += a1.f[k] * wv[k];
            d2 += a2.f[k] * wv[k];
            d3 += a3.f[k] * wv[k];
        }
        iacc += __float2int_rn(fmaxf(d0 + xv0, 0.f) * QSCALE);
        iacc += l1 ? __float2int_rn(fmaxf(d1 + xv1, 0.f) * QSCALE) : 0;
        iacc += l2 ? __float2int_rn(fmaxf(d2 + xv2, 0.f) * QSCALE) : 0;
        iacc += l3 ? __float2int_rn(fmaxf(d3 + xv3, 0.f) * QSCALE) : 0;
    }
    agg[(size_t)n * D + lane] = (float)iacc * (1.0f / QSCALE);
}

// =====================  path B fallback: atomic edge kernel  =================
__global__ __launch_bounds__(256) void edge_kernel(
    const float* __restrict__ x,
    const int*   __restrict__ ei32,
    const float* __restrict__ ea,
    const float* __restrict__ W_edge,
    const float* __restrict__ b_edge,
    float*       __restrict__ agg)
{
    __shared__ float s_ea[64 * ED];
    __shared__ int   s_src[64];
    __shared__ int   s_dst[64];

    const int tid  = threadIdx.x;
    const int lane = tid & 63;
    const int wave = tid >> 6;
    const long long ebase = (long long)blockIdx.x * 64;

    const int hi = ei32[2 * lane + 1];
    const bool is64 = !__any(hi != 0);

    float w[ED];
    #pragma unroll
    for (int i = 0; i < ED / 4; ++i) {
        float4 t = reinterpret_cast<const float4*>(W_edge)[lane * (ED / 4) + i];
        w[4*i+0] = t.x; w[4*i+1] = t.y; w[4*i+2] = t.z; w[4*i+3] = t.w;
    }
    const float bo = b_edge[lane];

    reinterpret_cast<float4*>(s_ea)[tid] =
        reinterpret_cast<const float4*>(ea + ebase * ED)[tid];

    if (tid < 64) {
        long long e = ebase + tid;
        s_src[tid] = is64 ? ei32[2 * e] : ei32[e];
    } else if (tid < 128) {
        long long e = ebase + (tid - 64);
        s_dst[tid - 64] = is64 ? ei32[2 * (NE + e)] : ei32[NE + e];
    }
    __syncthreads();

    #pragma unroll 4
    for (int i = 0; i < 16; ++i) {
        const int el = wave * 16 + i;
        float acc = bo;
        const float* er = s_ea + el * ED;
        #pragma unroll
        for (int k = 0; k < ED; ++k) acc += er[k] * w[k];
        const long long s = s_src[el];
        const long long d = s_dst[el];
        float m = fmaxf(acc + x[s * D + lane], 0.f);
        atomicAdd(&agg[d * D + lane], m);
    }
}

// =====================  node stages  =====================

__global__ __launch_bounds__(256) void node1_kernel(
    const float* __restrict__ x,
    const float* __restrict__ agg,
    const float* __restrict__ W1,
    const float* __restrict__ b1,
    float*       __restrict__ h1,
    float*       __restrict__ colsum,
    float*       __restrict__ colsumsq)
{
    __shared__ float s_h[64 * D];
    const int tid  = threadIdx.x;
    const int o    = tid & 63;
    const int wave = tid >> 6;
    const long long rbase = (long long)blockIdx.x * 64;

    float w[D];
    #pragma unroll
    for (int i = 0; i < D / 4; ++i) {
        float4 t = reinterpret_cast<const float4*>(W1)[o * (D / 4) + i];
        w[4*i+0] = t.x; w[4*i+1] = t.y; w[4*i+2] = t.z; w[4*i+3] = t.w;
    }

    #pragma unroll
    for (int i = 0; i < 4; ++i) {
        const int f4 = tid + 256 * i;
        const long long row = rbase + (f4 >> 4);
        float4 t = make_float4(0.f, 0.f, 0.f, 0.f);
        if (row < NN) {
            float4 a = reinterpret_cast<const float4*>(x)  [row * (D/4) + (f4 & 15)];
            float4 g = reinterpret_cast<const float4*>(agg)[row * (D/4) + (f4 & 15)];
            t.x = a.x + g.x; t.y = a.y + g.y; t.z = a.z + g.z; t.w = a.w + g.w;
        }
        reinterpret_cast<float4*>(s_h)[f4] = t;
    }
    __syncthreads();

    const float bb = b1[o];
    float psum = 0.f, psq = 0.f;
    for (int i = 0; i < 16; ++i) {
        const int r = wave + 4 * i;
        const long long row = rbase + r;
        float acc = bb;
        const float4* sr = reinterpret_cast<const float4*>(s_h + r * D);
        #pragma unroll
        for (int k = 0; k < D / 4; ++k) {
            float4 v = sr[k];
            acc += v.x * w[4*k+0] + v.y * w[4*k+1] + v.z * w[4*k+2] + v.w * w[4*k+3];
        }
        if (row < NN) {
            h1[row * D + o] = acc;
            psum += acc;
            psq  += acc * acc;
        }
    }
    __syncthreads();
    s_h[wave * 64 + o]       = psum;
    s_h[256 + wave * 64 + o] = psq;
    __syncthreads();
    if (tid < 64) {
        float s0 = s_h[tid] + s_h[64 + tid] + s_h[128 + tid] + s_h[192 + tid];
        float q0 = s_h[256 + tid] + s_h[320 + tid] + s_h[384 + tid] + s_h[448 + tid];
        atomicAdd(&colsum[tid], s0);
        atomicAdd(&colsumsq[tid], q0);
    }
}

__global__ void bnstats_kernel(
    const float* __restrict__ colsum,
    const float* __restrict__ colsumsq,
    const float* __restrict__ gamma,
    const float* __restrict__ beta,
    float*       __restrict__ scale,
    float*       __restrict__ shift)
{
    const int o = threadIdx.x;
    const float inv_n = 1.f / (float)NN;
    const float mean = colsum[o] * inv_n;
    const float var  = colsumsq[o] * inv_n - mean * mean;
    const float sc   = gamma[o] * rsqrtf(var + BN_EPS);
    scale[o] = sc;
    shift[o] = beta[o] - mean * sc;
}

__global__ __launch_bounds__(256) void node2_kernel(
    const float* __restrict__ h1,
    const float* __restrict__ scale,
    const float* __restrict__ shift,
    const float* __restrict__ W2,
    const float* __restrict__ b2,
    float*       __restrict__ out)
{
    __shared__ float s_a[64 * D];
    __shared__ float s_sc[D];
    __shared__ float s_sh[D];
    const int tid  = threadIdx.x;
    const int o    = tid & 63;
    const int wave = tid >> 6;
    const long long rbase = (long long)blockIdx.x * 64;

    if (tid < D) { s_sc[tid] = scale[tid]; s_sh[tid] = shift[tid]; }

    float w[D];
    #pragma unroll
    for (int i = 0; i < D / 4; ++i) {
        float4 t = reinterpret_cast<const float4*>(W2)[o * (D / 4) + i];
        w[4*i+0] = t.x; w[4*i+1] = t.y; w[4*i+2] = t.z; w[4*i+3] = t.w;
    }
    __syncthreads();

    #pragma unroll
    for (int i = 0; i < 4; ++i) {
        const int f4 = tid + 256 * i;
        const long long row = rbase + (f4 >> 4);
        float4 t = make_float4(0.f, 0.f, 0.f, 0.f);
        if (row < NN) {
            float4 v = reinterpret_cast<const float4*>(h1)[row * (D/4) + (f4 & 15)];
            const int c = (f4 & 15) * 4;
            t.x = fmaxf(v.x * s_sc[c+0] + s_sh[c+0], 0.f);
            t.y = fmaxf(v.y * s_sc[c+1] + s_sh[c+1], 0.f);
            t.z = fmaxf(v.z * s_sc[c+2] + s_sh[c+2], 0.f);
            t.w = fmaxf(v.w * s_sc[c+3] + s_sh[c+3], 0.f);
        }
        reinterpret_cast<float4*>(s_a)[f4] = t;
    }
    __syncthreads();

    const float bb = b2[o];
    for (int i = 0; i < 16; ++i) {
        const int r = wave + 4 * i;
        const long long row = rbase + r;
        float acc = bb;
        const float4* sr = reinterpret_cast<const float4*>(s_a + r * D);
        #pragma unroll
        for (int k = 0; k < D / 4; ++k) {
            float4 v = sr[k];
            acc += v.x * w[4*k+0] + v.y * w[4*k+1] + v.z * w[4*k+2] + v.w * w[4*k+3];
        }
        if (row < NN) out[row * D + o] = acc;
    }
}

// =====================  launch  =====================

extern "C" void kernel_launch(void* const* d_in, const int* in_sizes, int n_in,
                              void* d_out, int out_size, void* d_ws, size_t ws_size,
                              hipStream_t stream)
{
    const float* x      = (const float*)d_in[0];
    const int*   ei32   = (const int*)  d_in[1];
    const float* ea     = (const float*)d_in[2];
    const float* W_edge = (const float*)d_in[3];
    const float* b_edge = (const float*)d_in[4];
    const float* W1     = (const float*)d_in[5];
    const float* b1     = (const float*)d_in[6];
    const float* gamma  = (const float*)d_in[7];
    const float* beta   = (const float*)d_in[8];
    const float* W2     = (const float*)d_in[9];
    const float* b2     = (const float*)d_in[10];
    float* out = (float*)d_out;

    // tier-1 layout: agg | h1 | colsum..shift(256f) | bse | battr | xh | gcur
    float*    agg      = (float*)d_ws;                        // NN*D f32
    float*    h1       = agg + (size_t)NN * D;                // NN*D f32
    float*    colsum   = h1 + (size_t)NN * D;                 // 64
    float*    colsumsq = colsum + 64;                         // 64
    float*    scale    = colsumsq + 64;                       // 64
    float*    shift    = scale + 64;                          // 64
    unsigned* bse      = (unsigned*)(shift + 64);             // NBKT*BCAP u32
    __half*   battr    = (__half*)(bse + (size_t)NBKT * BCAP);// NBKT*BCAP*ED halves
    __half*   xh       = battr + (size_t)NBKT * BCAP * ED;    // NN*D halves
    int*      gcur     = (int*)(xh + (size_t)NN * D);         // NBKT

    const size_t need_t1 = (size_t)(2 * NN * D + 256) * 4
                         + (size_t)NBKT * BCAP * 4
                         + (size_t)NBKT * BCAP * ED * 2
                         + (size_t)NN * D * 2 + (size_t)NBKT * 4;

    // fallback layout (tiers 2-4): agg | h1 | cursor | colsum..(256f) | padded | xh
    int*    f_cursor = (int*)(h1 + (size_t)NN * D);
    float*  f_colsum = (float*)(f_cursor + NN);
    int2*   f_padded = (int2*)(f_colsum + 256);
    __half* f_xh     = (__half*)(f_padded + (size_t)NN * CAP);
    const size_t need_base = (size_t)(2 * NN * D + NN + 256) * 4 + (size_t)NN * CAP * 8;
    const size_t need_t2   = need_base + (size_t)NN * D * 2;

    if (ws_size >= need_t1) {
        hipMemsetAsync(gcur, 0, (size_t)NBKT * 4, stream);
        hipMemsetAsync(colsum, 0, 256 * 4, stream);           // BN accums every call
        xhalf_kernel<<<(NN * D / 4 + 255) / 256, 256, 0, stream>>>(x, xh);
        partA2_kernel<<<(NE + EPB2 - 1) / EPB2, 512, 0, stream>>>(ei32, ea, gcur, bse, battr);
        gather3_kernel<<<NBKT, 256, 0, stream>>>(bse, battr, gcur, xh, W_edge, b_edge, agg);
        node1_kernel<<<(NN + 63) / 64, 256, 0, stream>>>(x, agg, W1, b1, h1, colsum, colsumsq);
        bnstats_kernel<<<1, 64, 0, stream>>>(colsum, colsumsq, gamma, beta, scale, shift);
        node2_kernel<<<(NN + 63) / 64, 256, 0, stream>>>(h1, scale, shift, W2, b2, out);
        return;
    }

    if (ws_size >= need_t2) {
        hipMemsetAsync(f_cursor, 0, (size_t)(NN + 256) * 4, stream);
        xhalf_kernel<<<(NN * D / 4 + 255) / 256, 256, 0, stream>>>(x, f_xh);
        scatter_kernel<<<(NE + 255) / 256, 256, 0, stream>>>(ei32, f_cursor, f_padded);
        gather_kernel<true><<<(NN + 3) / 4, 256, 0, stream>>>(f_padded, f_cursor, x, f_xh, ea, W_edge, b_edge, agg);
    } else if (ws_size >= need_base) {
        hipMemsetAsync(f_cursor, 0, (size_t)(NN + 256) * 4, stream);
        scatter_kernel<<<(NE + 255) / 256, 256, 0, stream>>>(ei32, f_cursor, f_padded);
        gather_kernel<false><<<(NN + 3) / 4, 256, 0, stream>>>(f_padded, f_cursor, x, f_xh, ea, W_edge, b_edge, agg);
    } else {
        hipMemsetAsync(agg, 0, (size_t)NN * D * 4, stream);
        hipMemsetAsync(f_cursor, 0, (size_t)(NN + 256) * 4, stream);
        edge_kernel<<<NE / 64, 256, 0, stream>>>(x, ei32, ea, W_edge, b_edge, agg);
    }
    node1_kernel<<<(NN + 63) / 64, 256, 0, stream>>>(x, agg, W1, b1, h1, f_colsum, f_colsum + 64);
    bnstats_kernel<<<1, 64, 0, stream>>>(f_colsum, f_colsum + 64, gamma, beta, f_colsum + 128, f_colsum + 192);
    node2_kernel<<<(NN + 63) / 64, 256, 0, stream>>>(h1, f_colsum + 128, f_colsum + 192, W2, b2, out);
}

// Round 12
// 219.045 us; speedup vs baseline: 1.2285x; 1.2285x over previous
//
#include <hip/hip_runtime.h>
#include <hip/hip_fp16.h>

#define NN 50000
#define NE 1000000
#define D  64
#define ED 16
#define CAP 64
#define BN_EPS 1e-5f
#define QSCALE 1048576.0f           // 2^20 fixed-point scale for deterministic agg

// payload partition params (tier-1)
#define BSH  6                      // 64 nodes per bucket
#define NBKT 782                    // ceil(50000/64)
#define BCAP 1536                   // per-bucket capacity (mean 1279, +7 sigma)
#define EPB5 4096                   // edges per partA5 block

typedef _Float16 f16;
typedef _Float16 f16x2 __attribute__((ext_vector_type(2)));

struct alignas(16) SE8  { int v[8]; };        // fallback path
struct alignas(16) H16  { unsigned u[8]; };   // 16 halves (one fp16 attr row)
struct alignas(16) F16v { float f[16]; };     // fallback path

// =====================  x -> fp16 side copy  =====================
__global__ __launch_bounds__(256) void xhalf_kernel(
    const float* __restrict__ x, __half* __restrict__ xh)
{
    const int i = blockIdx.x * 256 + threadIdx.x;
    if (i >= NN * D / 4) return;
    const float4 a = reinterpret_cast<const float4*>(x)[i];
    ushort4 h;
    h.x = __half_as_ushort(__float2half(a.x));
    h.y = __half_as_ushort(__float2half(a.y));
    h.z = __half_as_ushort(__float2half(a.z));
    h.w = __half_as_ushort(__float2half(a.w));
    reinterpret_cast<ushort4*>(xh)[i] = h;
}

// ==== partA5: direct payload partition, NO scan.
//      ei/ea read coalesced (edge order); gpos = gbase + rank.  ====
__global__ __launch_bounds__(512) void partA5_kernel(
    const int*   __restrict__ ei32,
    const float* __restrict__ ea,
    int*         __restrict__ gcur,    // [NBKT], zeroed
    unsigned*    __restrict__ bse,     // [NBKT*BCAP]  src16|dst16
    __half*      __restrict__ battr)   // [NBKT*BCAP*ED] fp16 rows
{
    __shared__ int s_cnt[NBKT], s_cnt2[NBKT], s_gbase[NBKT];   // 9.4 KB

    const int tid = threadIdx.x;
    const long long base = (long long)blockIdx.x * EPB5;
    const int nedge = (int)(((long long)NE - base < EPB5) ? (NE - base) : EPB5);

    const int hi = ei32[2 * (tid & 63) + 1];
    const bool is64 = !__any(hi != 0);

    for (int i = tid; i < NBKT; i += 512) { s_cnt[i] = 0; s_cnt2[i] = 0; }
    __syncthreads();

    int srcv[8], dstv[8];
    #pragma unroll
    for (int i = 0; i < 8; ++i) {
        const int k = i * 512 + tid;
        int s = 0, d = 0;
        if (k < nedge) {
            const long long e = base + k;
            s = is64 ? ei32[2 * e]        : ei32[e];
            d = is64 ? ei32[2 * (NE + e)] : ei32[NE + e];
            atomicAdd(&s_cnt[d >> BSH], 1);
        }
        srcv[i] = s; dstv[i] = d;
    }
    __syncthreads();

    for (int i = tid; i < NBKT; i += 512)
        s_gbase[i] = s_cnt[i] ? atomicAdd(&gcur[i], s_cnt[i]) : 0;
    __syncthreads();

    // rank + payload write; ea rows read coalesced (lane t -> row base+k)
    #pragma unroll
    for (int i = 0; i < 8; ++i) {
        const int k = i * 512 + tid;
        if (k < nedge) {
            const int d = dstv[i], b = d >> BSH;
            const int r = atomicAdd(&s_cnt2[b], 1);
            const int gpos = s_gbase[b] + r;               // block's run is contiguous
            if (gpos < BCAP) {
                const float4* er = reinterpret_cast<const float4*>(ea + (base + k) * ED);
                const float4 f0 = er[0], f1 = er[1], f2 = er[2], f3 = er[3];
                unsigned u[8];
                u[0] = __half_as_ushort(__float2half(f0.x)) | ((unsigned)__half_as_ushort(__float2half(f0.y)) << 16);
                u[1] = __half_as_ushort(__float2half(f0.z)) | ((unsigned)__half_as_ushort(__float2half(f0.w)) << 16);
                u[2] = __half_as_ushort(__float2half(f1.x)) | ((unsigned)__half_as_ushort(__float2half(f1.y)) << 16);
                u[3] = __half_as_ushort(__float2half(f1.z)) | ((unsigned)__half_as_ushort(__float2half(f1.w)) << 16);
                u[4] = __half_as_ushort(__float2half(f2.x)) | ((unsigned)__half_as_ushort(__float2half(f2.y)) << 16);
                u[5] = __half_as_ushort(__float2half(f2.z)) | ((unsigned)__half_as_ushort(__float2half(f2.w)) << 16);
                u[6] = __half_as_ushort(__float2half(f3.x)) | ((unsigned)__half_as_ushort(__float2half(f3.y)) << 16);
                u[7] = __half_as_ushort(__float2half(f3.z)) | ((unsigned)__half_as_ushort(__float2half(f3.w)) << 16);
                bse[(size_t)b * BCAP + gpos] = (unsigned)srcv[i] | ((unsigned)d << 16);
                uint4* dst4 = reinterpret_cast<uint4*>(battr + ((size_t)b * BCAP + gpos) * ED);
                dst4[0] = make_uint4(u[0], u[1], u[2], u[3]);
                dst4[1] = make_uint4(u[4], u[5], u[6], u[7]);
            }
        }
    }
}

// ==== gather3c: one block per 64-node bucket, LDS int accumulate, float agg out ====
__global__ __launch_bounds__(256) void gather3c_kernel(
    const unsigned* __restrict__ bse,
    const __half*   __restrict__ battr,
    const int*      __restrict__ gcur,
    const __half*   __restrict__ xh,
    const float*    __restrict__ W_edge,
    const float*    __restrict__ b_edge,
    float*          __restrict__ agg)
{
    __shared__ int s_acc[64 * 64];   // 16 KB fixed-point accumulators
    const int tid  = threadIdx.x;
    const int lane = tid & 63;
    const int w    = tid >> 6;
    const int b    = blockIdx.x;

    for (int i = tid; i < 64 * 64; i += 256) s_acc[i] = 0;

    f16x2 wp[8];
    #pragma unroll
    for (int i = 0; i < 8; ++i) {
        const float2 t = reinterpret_cast<const float2*>(W_edge)[lane * 8 + i];
        f16x2 p; p.x = (f16)t.x; p.y = (f16)t.y;
        wp[i] = p;
    }
    const float bo = b_edge[lane];
    __syncthreads();

    const int cnt = __builtin_amdgcn_readfirstlane(min(gcur[b], BCAP));
    const int chunk = ((cnt + 15) >> 4) << 2;             // per-wave, mult of 4
    const int wstart = w * chunk;
    const int wend   = min(cnt, wstart + chunk);

    const unsigned* rowse = bse   + (size_t)b * BCAP;
    const __half*   rowat = battr + (size_t)b * BCAP * ED;

    if (wend > wstart) {
        const int G = (wend - wstart + 3) >> 2;

        auto LD_SE = [&](int g) -> uint4 {
            return *reinterpret_cast<const uint4*>(rowse + wstart + g * 4);
        };
        auto LD_GRP = [&](const uint4& s4, int g, H16 at[4], float xv[4],
                          int dl[4], bool lv[4]) {
            #pragma unroll
            for (int j = 0; j < 4; ++j) {
                const int idx = wstart + g * 4 + j;
                const bool lj = idx < wend;               // wave-uniform
                const unsigned sj = (j == 0) ? s4.x : (j == 1) ? s4.y
                                 : (j == 2) ? s4.z : s4.w;
                const unsigned se = lj ? sj : s4.x;
                const int src = __builtin_amdgcn_readfirstlane((int)(se & 0xffffu));
                dl[j] = __builtin_amdgcn_readfirstlane((int)((se >> 16) & 63u));
                const int ii = lj ? idx : (wstart + g * 4);
                at[j] = *reinterpret_cast<const H16*>(rowat + (size_t)ii * ED);
                xv[j] = __half2float(xh[(size_t)src * D + lane]);
                lv[j] = lj;
            }
        };
        auto COMP = [&](const H16 at[4], const float xv[4],
                        const int dl[4], const bool lv[4]) {
            #pragma unroll
            for (int j = 0; j < 4; ++j) {
                if (lv[j]) {                              // wave-uniform
                    float d = bo;
                    #pragma unroll
                    for (int k = 0; k < 8; ++k)
                        d = __builtin_amdgcn_fdot2(
                                __builtin_bit_cast(f16x2, at[j].u[k]), wp[k], d, false);
                    const float m = fmaxf(d + xv[j], 0.f);
                    atomicAdd(&s_acc[dl[j] * 64 + lane], __float2int_rn(m * QSCALE));
                }
            }
        };

        H16 atA[4], atB[4];
        float xvA[4], xvB[4];
        int dlA[4], dlB[4];
        bool lvA[4], lvB[4];
        uint4 sB = LD_SE(0);
        LD_GRP(sB, 0, atA, xvA, dlA, lvA);
        if (G > 1) sB = LD_SE(1);

        for (int g = 0; g < G; g += 2) {
            if (g + 1 < G) LD_GRP(sB, g + 1, atB, xvB, dlB, lvB);
            if (g + 2 < G) sB = LD_SE(g + 2);
            COMP(atA, xvA, dlA, lvA);
            if (g + 2 < G) LD_GRP(sB, g + 2, atA, xvA, dlA, lvA);
            if (g + 3 < G) sB = LD_SE(g + 3);
            if (g + 1 < G) COMP(atB, xvB, dlB, lvB);
        }
    }
    __syncthreads();

    const float inv = 1.0f / QSCALE;
    for (int r = w; r < 64; r += 4) {
        const int n = (b << BSH) + r;
        if (n < NN) agg[(size_t)n * D + lane] = (float)s_acc[r * 64 + lane] * inv;
    }
}

// ============== fallback scatter (global atomic slot assignment) =============
__global__ __launch_bounds__(256) void scatter_kernel(
    const int* __restrict__ ei32,
    int*       __restrict__ cursor,
    int2*      __restrict__ padded)
{
    const int e = blockIdx.x * 256 + threadIdx.x;
    const int hi = ei32[2 * (threadIdx.x & 63) + 1];
    const bool is64 = !__any(hi != 0);
    if (e >= NE) return;
    const int src = is64 ? ei32[2 * e]        : ei32[e];
    const int dst = is64 ? ei32[2 * (NE + e)] : ei32[NE + e];
    const int slot = atomicAdd(&cursor[dst], 1);
    if (slot < CAP) padded[(size_t)dst * CAP + slot] = make_int2(src, e);
}

// =============== fallback gather (R8): scalar-pipe f32 attrs ================
template<bool XH>
__global__ __launch_bounds__(256) void gather_kernel(
    const int2*  __restrict__ padded,
    const int*   __restrict__ cursor,
    const float* __restrict__ x,
    const __half* __restrict__ xh,
    const float* __restrict__ ea,
    const float* __restrict__ W_edge,
    const float* __restrict__ b_edge,
    float*       __restrict__ agg)
{
    const int tid  = threadIdx.x;
    const int lane = tid & 63;
    const int n = __builtin_amdgcn_readfirstlane(blockIdx.x * 4 + (tid >> 6));
    if (n >= NN) return;

    float wv[ED];
    #pragma unroll
    for (int i = 0; i < ED / 4; ++i) {
        float4 t = reinterpret_cast<const float4*>(W_edge)[lane * (ED / 4) + i];
        wv[4*i+0] = t.x; wv[4*i+1] = t.y; wv[4*i+2] = t.z; wv[4*i+3] = t.w;
    }
    const float bo = b_edge[lane];

    const int deg = __builtin_amdgcn_readfirstlane(min(cursor[n], CAP));
    const int2* row = padded + (size_t)n * CAP;

    int iacc = 0;
    for (int e0 = 0; e0 < deg; e0 += 4) {
        const SE8 g = *reinterpret_cast<const SE8*>(row + e0);
        const bool l1 = (e0 + 1 < deg), l2 = (e0 + 2 < deg), l3 = (e0 + 3 < deg);
        const int src0 = __builtin_amdgcn_readfirstlane(g.v[0]);
        const int eid0 = __builtin_amdgcn_readfirstlane(g.v[1]);
        const int src1 = __builtin_amdgcn_readfirstlane(l1 ? g.v[2] : g.v[0]);
        const int eid1 = __builtin_amdgcn_readfirstlane(l1 ? g.v[3] : g.v[1]);
        const int src2 = __builtin_amdgcn_readfirstlane(l2 ? g.v[4] : g.v[0]);
        const int eid2 = __builtin_amdgcn_readfirstlane(l2 ? g.v[5] : g.v[1]);
        const int src3 = __builtin_amdgcn_readfirstlane(l3 ? g.v[6] : g.v[0]);
        const int eid3 = __builtin_amdgcn_readfirstlane(l3 ? g.v[7] : g.v[1]);

        const F16v a0 = *reinterpret_cast<const F16v*>(ea + (size_t)eid0 * ED);
        const F16v a1 = *reinterpret_cast<const F16v*>(ea + (size_t)eid1 * ED);
        const F16v a2 = *reinterpret_cast<const F16v*>(ea + (size_t)eid2 * ED);
        const F16v a3 = *reinterpret_cast<const F16v*>(ea + (size_t)eid3 * ED);

        float xv0, xv1, xv2, xv3;
        if (XH) {
            xv0 = __half2float(xh[(size_t)src0 * D + lane]);
            xv1 = __half2float(xh[(size_t)src1 * D + lane]);
            xv2 = __half2float(xh[(size_t)src2 * D + lane]);
            xv3 = __half2float(xh[(size_t)src3 * D + lane]);
        } else {
            xv0 = x[(size_t)src0 * D + lane];
            xv1 = x[(size_t)src1 * D + lane];
            xv2 = x[(size_t)src2 * D + lane];
            xv3 = x[(size_t)src3 * D + lane];
        }

        float d0 = bo, d1 = bo, d2 = bo, d3 = bo;
        #pragma unroll
        for (int k = 0; k < ED; ++k) {
            d0 += a0.f[k] * wv[k];
            d1 += a1.f[k] * wv[k];
            d2 += a2.f[k] * wv[k];
            d3 += a3.f[k] * wv[k];
        }
        iacc += __float2int_rn(fmaxf(d0 + xv0, 0.f) * QSCALE);
        iacc += l1 ? __float2int_rn(fmaxf(d1 + xv1, 0.f) * QSCALE) : 0;
        iacc += l2 ? __float2int_rn(fmaxf(d2 + xv2, 0.f) * QSCALE) : 0;
        iacc += l3 ? __float2int_rn(fmaxf(d3 + xv3, 0.f) * QSCALE) : 0;
    }
    agg[(size_t)n * D + lane] = (float)iacc * (1.0f / QSCALE);
}

// =====================  path B fallback: atomic edge kernel  =================
__global__ __launch_bounds__(256) void edge_kernel(
    const float* __restrict__ x,
    const int*   __restrict__ ei32,
    const float* __restrict__ ea,
    const float* __restrict__ W_edge,
    const float* __restrict__ b_edge,
    float*       __restrict__ agg)
{
    __shared__ float s_ea[64 * ED];
    __shared__ int   s_src[64];
    __shared__ int   s_dst[64];

    const int tid  = threadIdx.x;
    const int lane = tid & 63;
    const int wave = tid >> 6;
    const long long ebase = (long long)blockIdx.x * 64;

    const int hi = ei32[2 * lane + 1];
    const bool is64 = !__any(hi != 0);

    float w[ED];
    #pragma unroll
    for (int i = 0; i < ED / 4; ++i) {
        float4 t = reinterpret_cast<const float4*>(W_edge)[lane * (ED / 4) + i];
        w[4*i+0] = t.x; w[4*i+1] = t.y; w[4*i+2] = t.z; w[4*i+3] = t.w;
    }
    const float bo = b_edge[lane];

    reinterpret_cast<float4*>(s_ea)[tid] =
        reinterpret_cast<const float4*>(ea + ebase * ED)[tid];

    if (tid < 64) {
        long long e = ebase + tid;
        s_src[tid] = is64 ? ei32[2 * e] : ei32[e];
    } else if (tid < 128) {
        long long e = ebase + (tid - 64);
        s_dst[tid - 64] = is64 ? ei32[2 * (NE + e)] : ei32[NE + e];
    }
    __syncthreads();

    #pragma unroll 4
    for (int i = 0; i < 16; ++i) {
        const int el = wave * 16 + i;
        float acc = bo;
        const float* er = s_ea + el * ED;
        #pragma unroll
        for (int k = 0; k < ED; ++k) acc += er[k] * w[k];
        const long long s = s_src[el];
        const long long d = s_dst[el];
        float m = fmaxf(acc + x[s * D + lane], 0.f);
        atomicAdd(&agg[d * D + lane], m);
    }
}

// =====================  node stages  =====================

__global__ __launch_bounds__(256) void node1_kernel(
    const float* __restrict__ x,
    const float* __restrict__ agg,
    const float* __restrict__ W1,
    const float* __restrict__ b1,
    float*       __restrict__ h1,
    float*       __restrict__ colsum,
    float*       __restrict__ colsumsq)
{
    __shared__ float s_h[64 * D];
    const int tid  = threadIdx.x;
    const int o    = tid & 63;
    const int wave = tid >> 6;
    const long long rbase = (long long)blockIdx.x * 64;

    float w[D];
    #pragma unroll
    for (int i = 0; i < D / 4; ++i) {
        float4 t = reinterpret_cast<const float4*>(W1)[o * (D / 4) + i];
        w[4*i+0] = t.x; w[4*i+1] = t.y; w[4*i+2] = t.z; w[4*i+3] = t.w;
    }

    #pragma unroll
    for (int i = 0; i < 4; ++i) {
        const int f4 = tid + 256 * i;
        const long long row = rbase + (f4 >> 4);
        float4 t = make_float4(0.f, 0.f, 0.f, 0.f);
        if (row < NN) {
            float4 a = reinterpret_cast<const float4*>(x)  [row * (D/4) + (f4 & 15)];
            float4 g = reinterpret_cast<const float4*>(agg)[row * (D/4) + (f4 & 15)];
            t.x = a.x + g.x; t.y = a.y + g.y; t.z = a.z + g.z; t.w = a.w + g.w;
        }
        reinterpret_cast<float4*>(s_h)[f4] = t;
    }
    __syncthreads();

    const float bb = b1[o];
    float psum = 0.f, psq = 0.f;
    for (int i = 0; i < 16; ++i) {
        const int r = wave + 4 * i;
        const long long row = rbase + r;
        float acc = bb;
        const float4* sr = reinterpret_cast<const float4*>(s_h + r * D);
        #pragma unroll
        for (int k = 0; k < D / 4; ++k) {
            float4 v = sr[k];
            acc += v.x * w[4*k+0] + v.y * w[4*k+1] + v.z * w[4*k+2] + v.w * w[4*k+3];
        }
        if (row < NN) {
            h1[row * D + o] = acc;
            psum += acc;
            psq  += acc * acc;
        }
    }
    __syncthreads();
    s_h[wave * 64 + o]       = psum;
    s_h[256 + wave * 64 + o] = psq;
    __syncthreads();
    if (tid < 64) {
        float s0 = s_h[tid] + s_h[64 + tid] + s_h[128 + tid] + s_h[192 + tid];
        float q0 = s_h[256 + tid] + s_h[320 + tid] + s_h[384 + tid] + s_h[448 + tid];
        atomicAdd(&colsum[tid], s0);
        atomicAdd(&colsumsq[tid], q0);
    }
}

__global__ void bnstats_kernel(
    const float* __restrict__ colsum,
    const float* __restrict__ colsumsq,
    const float* __restrict__ gamma,
    const float* __restrict__ beta,
    float*       __restrict__ scale,
    float*       __restrict__ shift)
{
    const int o = threadIdx.x;
    const float inv_n = 1.f / (float)NN;
    const float mean = colsum[o] * inv_n;
    const float var  = colsumsq[o] * inv_n - mean * mean;
    const float sc   = gamma[o] * rsqrtf(var + BN_EPS);
    scale[o] = sc;
    shift[o] = beta[o] - mean * sc;
}

__global__ __launch_bounds__(256) void node2_kernel(
    const float* __restrict__ h1,
    const float* __restrict__ scale,
    const float* __restrict__ shift,
    const float* __restrict__ W2,
    const float* __restrict__ b2,
    float*       __restrict__ out)
{
    __shared__ float s_a[64 * D];
    __shared__ float s_sc[D];
    __shared__ float s_sh[D];
    const int tid  = threadIdx.x;
    const int o    = tid & 63;
    const int wave = tid >> 6;
    const long long rbase = (long long)blockIdx.x * 64;

    if (tid < D) { s_sc[tid] = scale[tid]; s_sh[tid] = shift[tid]; }

    float w[D];
    #pragma unroll
    for (int i = 0; i < D / 4; ++i) {
        float4 t = reinterpret_cast<const float4*>(W2)[o * (D / 4) + i];
        w[4*i+0] = t.x; w[4*i+1] = t.y; w[4*i+2] = t.z; w[4*i+3] = t.w;
    }
    __syncthreads();

    #pragma unroll
    for (int i = 0; i < 4; ++i) {
        const int f4 = tid + 256 * i;
        const long long row = rbase + (f4 >> 4);
        float4 t = make_float4(0.f, 0.f, 0.f, 0.f);
        if (row < NN) {
            float4 v = reinterpret_cast<const float4*>(h1)[row * (D/4) + (f4 & 15)];
            const int c = (f4 & 15) * 4;
            t.x = fmaxf(v.x * s_sc[c+0] + s_sh[c+0], 0.f);
            t.y = fmaxf(v.y * s_sc[c+1] + s_sh[c+1], 0.f);
            t.z = fmaxf(v.z * s_sc[c+2] + s_sh[c+2], 0.f);
            t.w = fmaxf(v.w * s_sc[c+3] + s_sh[c+3], 0.f);
        }
        reinterpret_cast<float4*>(s_a)[f4] = t;
    }
    __syncthreads();

    const float bb = b2[o];
    for (int i = 0; i < 16; ++i) {
        const int r = wave + 4 * i;
        const long long row = rbase + r;
        float acc = bb;
        const float4* sr = reinterpret_cast<const float4*>(s_a + r * D);
        #pragma unroll
        for (int k = 0; k < D / 4; ++k) {
            float4 v = sr[k];
            acc += v.x * w[4*k+0] + v.y * w[4*k+1] + v.z * w[4*k+2] + v.w * w[4*k+3];
        }
        if (row < NN) out[row * D + o] = acc;
    }
}

// =====================  launch  =====================

extern "C" void kernel_launch(void* const* d_in, const int* in_sizes, int n_in,
                              void* d_out, int out_size, void* d_ws, size_t ws_size,
                              hipStream_t stream)
{
    const float* x      = (const float*)d_in[0];
    const int*   ei32   = (const int*)  d_in[1];
    const float* ea     = (const float*)d_in[2];
    const float* W_edge = (const float*)d_in[3];
    const float* b_edge = (const float*)d_in[4];
    const float* W1     = (const float*)d_in[5];
    const float* b1     = (const float*)d_in[6];
    const float* gamma  = (const float*)d_in[7];
    const float* beta   = (const float*)d_in[8];
    const float* W2     = (const float*)d_in[9];
    const float* b2     = (const float*)d_in[10];
    float* out = (float*)d_out;

    // tier-1 layout: agg | h1 | colsum..shift(256f) | bse | battr | xh | gcur
    float*    agg      = (float*)d_ws;                        // NN*D f32
    float*    h1       = agg + (size_t)NN * D;                // NN*D f32
    float*    colsum   = h1 + (size_t)NN * D;                 // 64
    float*    colsumsq = colsum + 64;
    float*    scale    = colsumsq + 64;
    float*    shift    = scale + 64;
    unsigned* bse      = (unsigned*)(colsum + 256);           // NBKT*BCAP u32
    __half*   battr    = (__half*)(bse + (size_t)NBKT * BCAP);// NBKT*BCAP*ED halves
    __half*   xh       = battr + (size_t)NBKT * BCAP * ED;    // NN*D halves
    int*      gcur     = (int*)(xh + (size_t)NN * D);         // NBKT

    const size_t need_t1 = (size_t)(2 * NN * D + 256) * 4
                         + (size_t)NBKT * BCAP * 4
                         + (size_t)NBKT * BCAP * ED * 2
                         + (size_t)NN * D * 2 + (size_t)NBKT * 4;

    // fallback layout (tiers 2-4): agg | h1f | cursor | colsum(256f) | padded | xh
    float*  f_agg    = (float*)d_ws;
    float*  f_h1     = f_agg + (size_t)NN * D;
    int*    f_cursor = (int*)(f_h1 + (size_t)NN * D);
    float*  f_colsum = (float*)(f_cursor + NN);
    int2*   f_padded = (int2*)(f_colsum + 256);
    __half* f_xh     = (__half*)(f_padded + (size_t)NN * CAP);
    const size_t need_base = (size_t)(2 * NN * D + NN + 256) * 4 + (size_t)NN * CAP * 8;
    const size_t need_t2   = need_base + (size_t)NN * D * 2;

    if (ws_size >= need_t1) {
        hipMemsetAsync(gcur, 0, (size_t)NBKT * 4, stream);
        hipMemsetAsync(colsum, 0, 256 * 4, stream);           // BN accums every call
        xhalf_kernel<<<(NN * D / 4 + 255) / 256, 256, 0, stream>>>(x, xh);
        partA5_kernel<<<(NE + EPB5 - 1) / EPB5, 512, 0, stream>>>(ei32, ea, gcur, bse, battr);
        gather3c_kernel<<<NBKT, 256, 0, stream>>>(bse, battr, gcur, xh, W_edge, b_edge, agg);
        node1_kernel<<<(NN + 63) / 64, 256, 0, stream>>>(x, agg, W1, b1, h1, colsum, colsumsq);
        bnstats_kernel<<<1, 64, 0, stream>>>(colsum, colsumsq, gamma, beta, scale, shift);
        node2_kernel<<<(NN + 63) / 64, 256, 0, stream>>>(h1, scale, shift, W2, b2, out);
        return;
    }

    if (ws_size >= need_t2) {
        hipMemsetAsync(f_cursor, 0, (size_t)(NN + 256) * 4, stream);
        xhalf_kernel<<<(NN * D / 4 + 255) / 256, 256, 0, stream>>>(x, f_xh);
        scatter_kernel<<<(NE + 255) / 256, 256, 0, stream>>>(ei32, f_cursor, f_padded);
        gather_kernel<true><<<(NN + 3) / 4, 256, 0, stream>>>(f_padded, f_cursor, x, f_xh, ea, W_edge, b_edge, f_agg);
    } else if (ws_size >= need_base) {
        hipMemsetAsync(f_cursor, 0, (size_t)(NN + 256) * 4, stream);
        scatter_kernel<<<(NE + 255) / 256, 256, 0, stream>>>(ei32, f_cursor, f_padded);
        gather_kernel<false><<<(NN + 3) / 4, 256, 0, stream>>>(f_padded, f_cursor, x, f_xh, ea, W_edge, b_edge, f_agg);
    } else {
        hipMemsetAsync(f_agg, 0, (size_t)NN * D * 4, stream);
        hipMemsetAsync(f_cursor, 0, (size_t)(NN + 256) * 4, stream);
        edge_kernel<<<NE / 64, 256, 0, stream>>>(x, ei32, ea, W_edge, b_edge, f_agg);
    }
    node1_kernel<<<(NN + 63) / 64, 256, 0, stream>>>(x, f_agg, W1, b1, f_h1, f_colsum, f_colsum + 64);
    bnstats_kernel<<<1, 64, 0, stream>>>(f_colsum, f_colsum + 64, gamma, beta, f_colsum + 128, f_colsum + 192);
    node2_kernel<<<(NN + 63) / 64, 256, 0, stream>>>(f_h1, f_colsum + 128, f_colsum + 192, W2, b2, out);
}

// Round 13
// 216.655 us; speedup vs baseline: 1.2421x; 1.0110x over previous
//
#include <hip/hip_runtime.h>
#include <hip/hip_fp16.h>

#define NN 50000
#define NE 1000000
#define D  64
#define ED 16
#define CAP 64
#define BN_EPS 1e-5f
#define QSCALE 1048576.0f           // 2^20 fixed-point scale for deterministic agg

// payload partition params (tier-1)
#define BSH  6                      // 64 nodes per bucket
#define NBKT 782                    // ceil(50000/64)
#define BCAP 1536                   // per-bucket capacity (mean 1279, +7 sigma)
#define EPB5 4096                   // edges per partA5 block
#define GW   8                      // gather waves per block (512 threads)

typedef _Float16 f16;
typedef _Float16 f16x2 __attribute__((ext_vector_type(2)));

struct alignas(16) SE8  { int v[8]; };        // fallback path
struct alignas(16) H16  { unsigned u[8]; };   // 16 halves (one fp16 attr row)
struct alignas(16) F16v { float f[16]; };     // fallback path

// =====================  x -> fp16 side copy  =====================
__global__ __launch_bounds__(256) void xhalf_kernel(
    const float* __restrict__ x, __half* __restrict__ xh)
{
    const int i = blockIdx.x * 256 + threadIdx.x;
    if (i >= NN * D / 4) return;
    const float4 a = reinterpret_cast<const float4*>(x)[i];
    ushort4 h;
    h.x = __half_as_ushort(__float2half(a.x));
    h.y = __half_as_ushort(__float2half(a.y));
    h.z = __half_as_ushort(__float2half(a.z));
    h.w = __half_as_ushort(__float2half(a.w));
    reinterpret_cast<ushort4*>(xh)[i] = h;
}

// ==== partA5: direct payload partition, NO scan.
//      ei/ea read coalesced (edge order); gpos = gbase + rank.  ====
__global__ __launch_bounds__(512) void partA5_kernel(
    const int*   __restrict__ ei32,
    const float* __restrict__ ea,
    int*         __restrict__ gcur,    // [NBKT], zeroed
    unsigned*    __restrict__ bse,     // [NBKT*BCAP]  src16|dst16
    __half*      __restrict__ battr)   // [NBKT*BCAP*ED] fp16 rows
{
    __shared__ int s_cnt[NBKT], s_cnt2[NBKT], s_gbase[NBKT];   // 9.4 KB

    const int tid = threadIdx.x;
    const long long base = (long long)blockIdx.x * EPB5;
    const int nedge = (int)(((long long)NE - base < EPB5) ? (NE - base) : EPB5);

    const int hi = ei32[2 * (tid & 63) + 1];
    const bool is64 = !__any(hi != 0);

    for (int i = tid; i < NBKT; i += 512) { s_cnt[i] = 0; s_cnt2[i] = 0; }
    __syncthreads();

    int srcv[8], dstv[8];
    #pragma unroll
    for (int i = 0; i < 8; ++i) {
        const int k = i * 512 + tid;
        int s = 0, d = 0;
        if (k < nedge) {
            const long long e = base + k;
            s = is64 ? ei32[2 * e]        : ei32[e];
            d = is64 ? ei32[2 * (NE + e)] : ei32[NE + e];
            atomicAdd(&s_cnt[d >> BSH], 1);
        }
        srcv[i] = s; dstv[i] = d;
    }
    __syncthreads();

    for (int i = tid; i < NBKT; i += 512)
        s_gbase[i] = s_cnt[i] ? atomicAdd(&gcur[i], s_cnt[i]) : 0;
    __syncthreads();

    // rank + payload write; ea rows read coalesced (lane t -> row base+k)
    #pragma unroll
    for (int i = 0; i < 8; ++i) {
        const int k = i * 512 + tid;
        if (k < nedge) {
            const int d = dstv[i], b = d >> BSH;
            const int r = atomicAdd(&s_cnt2[b], 1);
            const int gpos = s_gbase[b] + r;               // block's run is contiguous
            if (gpos < BCAP) {
                const float4* er = reinterpret_cast<const float4*>(ea + (base + k) * ED);
                const float4 f0 = er[0], f1 = er[1], f2 = er[2], f3 = er[3];
                unsigned u[8];
                u[0] = __half_as_ushort(__float2half(f0.x)) | ((unsigned)__half_as_ushort(__float2half(f0.y)) << 16);
                u[1] = __half_as_ushort(__float2half(f0.z)) | ((unsigned)__half_as_ushort(__float2half(f0.w)) << 16);
                u[2] = __half_as_ushort(__float2half(f1.x)) | ((unsigned)__half_as_ushort(__float2half(f1.y)) << 16);
                u[3] = __half_as_ushort(__float2half(f1.z)) | ((unsigned)__half_as_ushort(__float2half(f1.w)) << 16);
                u[4] = __half_as_ushort(__float2half(f2.x)) | ((unsigned)__half_as_ushort(__float2half(f2.y)) << 16);
                u[5] = __half_as_ushort(__float2half(f2.z)) | ((unsigned)__half_as_ushort(__float2half(f2.w)) << 16);
                u[6] = __half_as_ushort(__float2half(f3.x)) | ((unsigned)__half_as_ushort(__float2half(f3.y)) << 16);
                u[7] = __half_as_ushort(__float2half(f3.z)) | ((unsigned)__half_as_ushort(__float2half(f3.w)) << 16);
                bse[(size_t)b * BCAP + gpos] = (unsigned)srcv[i] | ((unsigned)d << 16);
                uint4* dst4 = reinterpret_cast<uint4*>(battr + ((size_t)b * BCAP + gpos) * ED);
                dst4[0] = make_uint4(u[0], u[1], u[2], u[3]);
                dst4[1] = make_uint4(u[4], u[5], u[6], u[7]);
            }
        }
    }
}

// ==== gather3d: one 512-thread block (8 waves) per 64-node bucket ====
__global__ __launch_bounds__(512) void gather3d_kernel(
    const unsigned* __restrict__ bse,
    const __half*   __restrict__ battr,
    const int*      __restrict__ gcur,
    const __half*   __restrict__ xh,
    const float*    __restrict__ W_edge,
    const float*    __restrict__ b_edge,
    float*          __restrict__ agg)
{
    __shared__ int s_acc[64 * 64];   // 16 KB fixed-point accumulators
    const int tid  = threadIdx.x;
    const int lane = tid & 63;
    const int w    = tid >> 6;       // 0..7
    const int b    = blockIdx.x;

    for (int i = tid; i < 64 * 64; i += 512) s_acc[i] = 0;

    f16x2 wp[8];
    #pragma unroll
    for (int i = 0; i < 8; ++i) {
        const float2 t = reinterpret_cast<const float2*>(W_edge)[lane * 8 + i];
        f16x2 p; p.x = (f16)t.x; p.y = (f16)t.y;
        wp[i] = p;
    }
    const float bo = b_edge[lane];
    __syncthreads();

    const int cnt = __builtin_amdgcn_readfirstlane(min(gcur[b], BCAP));
    const int chunk = ((cnt + GW * 4 - 1) / (GW * 4)) * 4;   // per-wave, mult of 4
    const int wstart = w * chunk;
    const int wend   = min(cnt, wstart + chunk);

    const unsigned* rowse = bse   + (size_t)b * BCAP;
    const __half*   rowat = battr + (size_t)b * BCAP * ED;

    if (wend > wstart) {
        const int G = (wend - wstart + 3) >> 2;

        auto LD_SE = [&](int g) -> uint4 {
            return *reinterpret_cast<const uint4*>(rowse + wstart + g * 4);
        };
        auto LD_GRP = [&](const uint4& s4, int g, H16 at[4], float xv[4],
                          int dl[4], bool lv[4]) {
            #pragma unroll
            for (int j = 0; j < 4; ++j) {
                const int idx = wstart + g * 4 + j;
                const bool lj = idx < wend;               // wave-uniform
                const unsigned sj = (j == 0) ? s4.x : (j == 1) ? s4.y
                                 : (j == 2) ? s4.z : s4.w;
                const unsigned se = lj ? sj : s4.x;
                const int src = __builtin_amdgcn_readfirstlane((int)(se & 0xffffu));
                dl[j] = __builtin_amdgcn_readfirstlane((int)((se >> 16) & 63u));
                const int ii = lj ? idx : (wstart + g * 4);
                at[j] = *reinterpret_cast<const H16*>(rowat + (size_t)ii * ED);
                xv[j] = __half2float(xh[(size_t)src * D + lane]);
                lv[j] = lj;
            }
        };
        auto COMP = [&](const H16 at[4], const float xv[4],
                        const int dl[4], const bool lv[4]) {
            #pragma unroll
            for (int j = 0; j < 4; ++j) {
                if (lv[j]) {                              // wave-uniform
                    float d = bo;
                    #pragma unroll
                    for (int k = 0; k < 8; ++k)
                        d = __builtin_amdgcn_fdot2(
                                __builtin_bit_cast(f16x2, at[j].u[k]), wp[k], d, false);
                    const float m = fmaxf(d + xv[j], 0.f);
                    atomicAdd(&s_acc[dl[j] * 64 + lane], __float2int_rn(m * QSCALE));
                }
            }
        };

        H16 atA[4], atB[4];
        float xvA[4], xvB[4];
        int dlA[4], dlB[4];
        bool lvA[4], lvB[4];
        uint4 sB = LD_SE(0);
        LD_GRP(sB, 0, atA, xvA, dlA, lvA);
        if (G > 1) sB = LD_SE(1);

        for (int g = 0; g < G; g += 2) {
            if (g + 1 < G) LD_GRP(sB, g + 1, atB, xvB, dlB, lvB);
            if (g + 2 < G) sB = LD_SE(g + 2);
            COMP(atA, xvA, dlA, lvA);
            if (g + 2 < G) LD_GRP(sB, g + 2, atA, xvA, dlA, lvA);
            if (g + 3 < G) sB = LD_SE(g + 3);
            if (g + 1 < G) COMP(atB, xvB, dlB, lvB);
        }
    }
    __syncthreads();

    const float inv = 1.0f / QSCALE;
    for (int r = w; r < 64; r += GW) {
        const int n = (b << BSH) + r;
        if (n < NN) agg[(size_t)n * D + lane] = (float)s_acc[r * 64 + lane] * inv;
    }
}

// ============== fallback scatter (global atomic slot assignment) =============
__global__ __launch_bounds__(256) void scatter_kernel(
    const int* __restrict__ ei32,
    int*       __restrict__ cursor,
    int2*      __restrict__ padded)
{
    const int e = blockIdx.x * 256 + threadIdx.x;
    const int hi = ei32[2 * (threadIdx.x & 63) + 1];
    const bool is64 = !__any(hi != 0);
    if (e >= NE) return;
    const int src = is64 ? ei32[2 * e]        : ei32[e];
    const int dst = is64 ? ei32[2 * (NE + e)] : ei32[NE + e];
    const int slot = atomicAdd(&cursor[dst], 1);
    if (slot < CAP) padded[(size_t)dst * CAP + slot] = make_int2(src, e);
}

// =============== fallback gather (R8): scalar-pipe f32 attrs ================
template<bool XH>
__global__ __launch_bounds__(256) void gather_kernel(
    const int2*  __restrict__ padded,
    const int*   __restrict__ cursor,
    const float* __restrict__ x,
    const __half* __restrict__ xh,
    const float* __restrict__ ea,
    const float* __restrict__ W_edge,
    const float* __restrict__ b_edge,
    float*       __restrict__ agg)
{
    const int tid  = threadIdx.x;
    const int lane = tid & 63;
    const int n = __builtin_amdgcn_readfirstlane(blockIdx.x * 4 + (tid >> 6));
    if (n >= NN) return;

    float wv[ED];
    #pragma unroll
    for (int i = 0; i < ED / 4; ++i) {
        float4 t = reinterpret_cast<const float4*>(W_edge)[lane * (ED / 4) + i];
        wv[4*i+0] = t.x; wv[4*i+1] = t.y; wv[4*i+2] = t.z; wv[4*i+3] = t.w;
    }
    const float bo = b_edge[lane];

    const int deg = __builtin_amdgcn_readfirstlane(min(cursor[n], CAP));
    const int2* row = padded + (size_t)n * CAP;

    int iacc = 0;
    for (int e0 = 0; e0 < deg; e0 += 4) {
        const SE8 g = *reinterpret_cast<const SE8*>(row + e0);
        const bool l1 = (e0 + 1 < deg), l2 = (e0 + 2 < deg), l3 = (e0 + 3 < deg);
        const int src0 = __builtin_amdgcn_readfirstlane(g.v[0]);
        const int eid0 = __builtin_amdgcn_readfirstlane(g.v[1]);
        const int src1 = __builtin_amdgcn_readfirstlane(l1 ? g.v[2] : g.v[0]);
        const int eid1 = __builtin_amdgcn_readfirstlane(l1 ? g.v[3] : g.v[1]);
        const int src2 = __builtin_amdgcn_readfirstlane(l2 ? g.v[4] : g.v[0]);
        const int eid2 = __builtin_amdgcn_readfirstlane(l2 ? g.v[5] : g.v[1]);
        const int src3 = __builtin_amdgcn_readfirstlane(l3 ? g.v[6] : g.v[0]);
        const int eid3 = __builtin_amdgcn_readfirstlane(l3 ? g.v[7] : g.v[1]);

        const F16v a0 = *reinterpret_cast<const F16v*>(ea + (size_t)eid0 * ED);
        const F16v a1 = *reinterpret_cast<const F16v*>(ea + (size_t)eid1 * ED);
        const F16v a2 = *reinterpret_cast<const F16v*>(ea + (size_t)eid2 * ED);
        const F16v a3 = *reinterpret_cast<const F16v*>(ea + (size_t)eid3 * ED);

        float xv0, xv1, xv2, xv3;
        if (XH) {
            xv0 = __half2float(xh[(size_t)src0 * D + lane]);
            xv1 = __half2float(xh[(size_t)src1 * D + lane]);
            xv2 = __half2float(xh[(size_t)src2 * D + lane]);
            xv3 = __half2float(xh[(size_t)src3 * D + lane]);
        } else {
            xv0 = x[(size_t)src0 * D + lane];
            xv1 = x[(size_t)src1 * D + lane];
            xv2 = x[(size_t)src2 * D + lane];
            xv3 = x[(size_t)src3 * D + lane];
        }

        float d0 = bo, d1 = bo, d2 = bo, d3 = bo;
        #pragma unroll
        for (int k = 0; k < ED; ++k) {
            d0 += a0.f[k] * wv[k];
            d1 += a1.f[k] * wv[k];
            d2 += a2.f[k] * wv[k];
            d3 += a3.f[k] * wv[k];
        }
        iacc += __float2int_rn(fmaxf(d0 + xv0, 0.f) * QSCALE);
        iacc += l1 ? __float2int_rn(fmaxf(d1 + xv1, 0.f) * QSCALE) : 0;
        iacc += l2 ? __float2int_rn(fmaxf(d2 + xv2, 0.f) * QSCALE) : 0;
        iacc += l3 ? __float2int_rn(fmaxf(d3 + xv3, 0.f) * QSCALE) : 0;
    }
    agg[(size_t)n * D + lane] = (float)iacc * (1.0f / QSCALE);
}

// =====================  path B fallback: atomic edge kernel  =================
__global__ __launch_bounds__(256) void edge_kernel(
    const float* __restrict__ x,
    const int*   __restrict__ ei32,
    const float* __restrict__ ea,
    const float* __restrict__ W_edge,
    const float* __restrict__ b_edge,
    float*       __restrict__ agg)
{
    __shared__ float s_ea[64 * ED];
    __shared__ int   s_src[64];
    __shared__ int   s_dst[64];

    const int tid  = threadIdx.x;
    const int lane = tid & 63;
    const int wave = tid >> 6;
    const long long ebase = (long long)blockIdx.x * 64;

    const int hi = ei32[2 * lane + 1];
    const bool is64 = !__any(hi != 0);

    float w[ED];
    #pragma unroll
    for (int i = 0; i < ED / 4; ++i) {
        float4 t = reinterpret_cast<const float4*>(W_edge)[lane * (ED / 4) + i];
        w[4*i+0] = t.x; w[4*i+1] = t.y; w[4*i+2] = t.z; w[4*i+3] = t.w;
    }
    const float bo = b_edge[lane];

    reinterpret_cast<float4*>(s_ea)[tid] =
        reinterpret_cast<const float4*>(ea + ebase * ED)[tid];

    if (tid < 64) {
        long long e = ebase + tid;
        s_src[tid] = is64 ? ei32[2 * e] : ei32[e];
    } else if (tid < 128) {
        long long e = ebase + (tid - 64);
        s_dst[tid - 64] = is64 ? ei32[2 * (NE + e)] : ei32[NE + e];
    }
    __syncthreads();

    #pragma unroll 4
    for (int i = 0; i < 16; ++i) {
        const int el = wave * 16 + i;
        float acc = bo;
        const float* er = s_ea + el * ED;
        #pragma unroll
        for (int k = 0; k < ED; ++k) acc += er[k] * w[k];
        const long long s = s_src[el];
        const long long d = s_dst[el];
        float m = fmaxf(acc + x[s * D + lane], 0.f);
        atomicAdd(&agg[d * D + lane], m);
    }
}

// =====================  node stages  =====================

__global__ __launch_bounds__(256) void node1_kernel(
    const float* __restrict__ x,
    const float* __restrict__ agg,
    const float* __restrict__ W1,
    const float* __restrict__ b1,
    float*       __restrict__ h1,
    float*       __restrict__ colsum,
    float*       __restrict__ colsumsq)
{
    __shared__ float s_h[64 * D];
    const int tid  = threadIdx.x;
    const int o    = tid & 63;
    const int wave = tid >> 6;
    const long long rbase = (long long)blockIdx.x * 64;

    float w[D];
    #pragma unroll
    for (int i = 0; i < D / 4; ++i) {
        float4 t = reinterpret_cast<const float4*>(W1)[o * (D / 4) + i];
        w[4*i+0] = t.x; w[4*i+1] = t.y; w[4*i+2] = t.z; w[4*i+3] = t.w;
    }

    #pragma unroll
    for (int i = 0; i < 4; ++i) {
        const int f4 = tid + 256 * i;
        const long long row = rbase + (f4 >> 4);
        float4 t = make_float4(0.f, 0.f, 0.f, 0.f);
        if (row < NN) {
            float4 a = reinterpret_cast<const float4*>(x)  [row * (D/4) + (f4 & 15)];
            float4 g = reinterpret_cast<const float4*>(agg)[row * (D/4) + (f4 & 15)];
            t.x = a.x + g.x; t.y = a.y + g.y; t.z = a.z + g.z; t.w = a.w + g.w;
        }
        reinterpret_cast<float4*>(s_h)[f4] = t;
    }
    __syncthreads();

    const float bb = b1[o];
    float psum = 0.f, psq = 0.f;
    for (int i = 0; i < 16; ++i) {
        const int r = wave + 4 * i;
        const long long row = rbase + r;
        float acc = bb;
        const float4* sr = reinterpret_cast<const float4*>(s_h + r * D);
        #pragma unroll
        for (int k = 0; k < D / 4; ++k) {
            float4 v = sr[k];
            acc += v.x * w[4*k+0] + v.y * w[4*k+1] + v.z * w[4*k+2] + v.w * w[4*k+3];
        }
        if (row < NN) {
            h1[row * D + o] = acc;
            psum += acc;
            psq  += acc * acc;
        }
    }
    __syncthreads();
    s_h[wave * 64 + o]       = psum;
    s_h[256 + wave * 64 + o] = psq;
    __syncthreads();
    if (tid < 64) {
        float s0 = s_h[tid] + s_h[64 + tid] + s_h[128 + tid] + s_h[192 + tid];
        float q0 = s_h[256 + tid] + s_h[320 + tid] + s_h[384 + tid] + s_h[448 + tid];
        atomicAdd(&colsum[tid], s0);
        atomicAdd(&colsumsq[tid], q0);
    }
}

__global__ void bnstats_kernel(
    const float* __restrict__ colsum,
    const float* __restrict__ colsumsq,
    const float* __restrict__ gamma,
    const float* __restrict__ beta,
    float*       __restrict__ scale,
    float*       __restrict__ shift)
{
    const int o = threadIdx.x;
    const float inv_n = 1.f / (float)NN;
    const float mean = colsum[o] * inv_n;
    const float var  = colsumsq[o] * inv_n - mean * mean;
    const float sc   = gamma[o] * rsqrtf(var + BN_EPS);
    scale[o] = sc;
    shift[o] = beta[o] - mean * sc;
}

__global__ __launch_bounds__(256) void node2_kernel(
    const float* __restrict__ h1,
    const float* __restrict__ scale,
    const float* __restrict__ shift,
    const float* __restrict__ W2,
    const float* __restrict__ b2,
    float*       __restrict__ out)
{
    __shared__ float s_a[64 * D];
    __shared__ float s_sc[D];
    __shared__ float s_sh[D];
    const int tid  = threadIdx.x;
    const int o    = tid & 63;
    const int wave = tid >> 6;
    const long long rbase = (long long)blockIdx.x * 64;

    if (tid < D) { s_sc[tid] = scale[tid]; s_sh[tid] = shift[tid]; }

    float w[D];
    #pragma unroll
    for (int i = 0; i < D / 4; ++i) {
        float4 t = reinterpret_cast<const float4*>(W2)[o * (D / 4) + i];
        w[4*i+0] = t.x; w[4*i+1] = t.y; w[4*i+2] = t.z; w[4*i+3] = t.w;
    }
    __syncthreads();

    #pragma unroll
    for (int i = 0; i < 4; ++i) {
        const int f4 = tid + 256 * i;
        const long long row = rbase + (f4 >> 4);
        float4 t = make_float4(0.f, 0.f, 0.f, 0.f);
        if (row < NN) {
            float4 v = reinterpret_cast<const float4*>(h1)[row * (D/4) + (f4 & 15)];
            const int c = (f4 & 15) * 4;
            t.x = fmaxf(v.x * s_sc[c+0] + s_sh[c+0], 0.f);
            t.y = fmaxf(v.y * s_sc[c+1] + s_sh[c+1], 0.f);
            t.z = fmaxf(v.z * s_sc[c+2] + s_sh[c+2], 0.f);
            t.w = fmaxf(v.w * s_sc[c+3] + s_sh[c+3], 0.f);
        }
        reinterpret_cast<float4*>(s_a)[f4] = t;
    }
    __syncthreads();

    const float bb = b2[o];
    for (int i = 0; i < 16; ++i) {
        const int r = wave + 4 * i;
        const long long row = rbase + r;
        float acc = bb;
        const float4* sr = reinterpret_cast<const float4*>(s_a + r * D);
        #pragma unroll
        for (int k = 0; k < D / 4; ++k) {
            float4 v = sr[k];
            acc += v.x * w[4*k+0] + v.y * w[4*k+1] + v.z * w[4*k+2] + v.w * w[4*k+3];
        }
        if (row < NN) out[row * D + o] = acc;
    }
}

// =====================  launch  =====================

extern "C" void kernel_launch(void* const* d_in, const int* in_sizes, int n_in,
                              void* d_out, int out_size, void* d_ws, size_t ws_size,
                              hipStream_t stream)
{
    const float* x      = (const float*)d_in[0];
    const int*   ei32   = (const int*)  d_in[1];
    const float* ea     = (const float*)d_in[2];
    const float* W_edge = (const float*)d_in[3];
    const float* b_edge = (const float*)d_in[4];
    const float* W1     = (const float*)d_in[5];
    const float* b1     = (const float*)d_in[6];
    const float* gamma  = (const float*)d_in[7];
    const float* beta   = (const float*)d_in[8];
    const float* W2     = (const float*)d_in[9];
    const float* b2     = (const float*)d_in[10];
    float* out = (float*)d_out;

    // tier-1 layout: agg | h1 | colsum..shift(256f) | bse | battr | xh | gcur
    float*    agg      = (float*)d_ws;                        // NN*D f32
    float*    h1       = agg + (size_t)NN * D;                // NN*D f32
    float*    colsum   = h1 + (size_t)NN * D;                 // 64
    float*    colsumsq = colsum + 64;
    float*    scale    = colsumsq + 64;
    float*    shift    = scale + 64;
    unsigned* bse      = (unsigned*)(colsum + 256);           // NBKT*BCAP u32
    __half*   battr    = (__half*)(bse + (size_t)NBKT * BCAP);// NBKT*BCAP*ED halves
    __half*   xh       = battr + (size_t)NBKT * BCAP * ED;    // NN*D halves
    int*      gcur     = (int*)(xh + (size_t)NN * D);         // NBKT

    const size_t need_t1 = (size_t)(2 * NN * D + 256) * 4
                         + (size_t)NBKT * BCAP * 4
                         + (size_t)NBKT * BCAP * ED * 2
                         + (size_t)NN * D * 2 + (size_t)NBKT * 4;

    // fallback layout (tiers 2-4): agg | h1f | cursor | colsum(256f) | padded | xh
    float*  f_agg    = (float*)d_ws;
    float*  f_h1     = f_agg + (size_t)NN * D;
    int*    f_cursor = (int*)(f_h1 + (size_t)NN * D);
    float*  f_colsum = (float*)(f_cursor + NN);
    int2*   f_padded = (int2*)(f_colsum + 256);
    __half* f_xh     = (__half*)(f_padded + (size_t)NN * CAP);
    const size_t need_base = (size_t)(2 * NN * D + NN + 256) * 4 + (size_t)NN * CAP * 8;
    const size_t need_t2   = need_base + (size_t)NN * D * 2;

    if (ws_size >= need_t1) {
        hipMemsetAsync(gcur, 0, (size_t)NBKT * 4, stream);
        hipMemsetAsync(colsum, 0, 256 * 4, stream);           // BN accums every call
        xhalf_kernel<<<(NN * D / 4 + 255) / 256, 256, 0, stream>>>(x, xh);
        partA5_kernel<<<(NE + EPB5 - 1) / EPB5, 512, 0, stream>>>(ei32, ea, gcur, bse, battr);
        gather3d_kernel<<<NBKT, 512, 0, stream>>>(bse, battr, gcur, xh, W_edge, b_edge, agg);
        node1_kernel<<<(NN + 63) / 64, 256, 0, stream>>>(x, agg, W1, b1, h1, colsum, colsumsq);
        bnstats_kernel<<<1, 64, 0, stream>>>(colsum, colsumsq, gamma, beta, scale, shift);
        node2_kernel<<<(NN + 63) / 64, 256, 0, stream>>>(h1, scale, shift, W2, b2, out);
        return;
    }

    if (ws_size >= need_t2) {
        hipMemsetAsync(f_cursor, 0, (size_t)(NN + 256) * 4, stream);
        xhalf_kernel<<<(NN * D / 4 + 255) / 256, 256, 0, stream>>>(x, f_xh);
        scatter_kernel<<<(NE + 255) / 256, 256, 0, stream>>>(ei32, f_cursor, f_padded);
        gather_kernel<true><<<(NN + 3) / 4, 256, 0, stream>>>(f_padded, f_cursor, x, f_xh, ea, W_edge, b_edge, f_agg);
    } else if (ws_size >= need_base) {
        hipMemsetAsync(f_cursor, 0, (size_t)(NN + 256) * 4, stream);
        scatter_kernel<<<(NE + 255) / 256, 256, 0, stream>>>(ei32, f_cursor, f_padded);
        gather_kernel<false><<<(NN + 3) / 4, 256, 0, stream>>>(f_padded, f_cursor, x, f_xh, ea, W_edge, b_edge, f_agg);
    } else {
        hipMemsetAsync(f_agg, 0, (size_t)NN * D * 4, stream);
        hipMemsetAsync(f_cursor, 0, (size_t)(NN + 256) * 4, stream);
        edge_kernel<<<NE / 64, 256, 0, stream>>>(x, ei32, ea, W_edge, b_edge, f_agg);
    }
    node1_kernel<<<(NN + 63) / 64, 256, 0, stream>>>(x, f_agg, W1, b1, f_h1, f_colsum, f_colsum + 64);
    bnstats_kernel<<<1, 64, 0, stream>>>(f_colsum, f_colsum + 64, gamma, beta, f_colsum + 128, f_colsum + 192);
    node2_kernel<<<(NN + 63) / 64, 256, 0, stream>>>(f_h1, f_colsum + 128, f_colsum + 192, W2, b2, out);
}

// Round 14
// 184.982 us; speedup vs baseline: 1.4548x; 1.1712x over previous
//
#include <hip/hip_runtime.h>
#include <hip/hip_fp16.h>

#define NN 50000
#define NE 1000000
#define D  64
#define ED 16
#define CAP 64
#define BN_EPS 1e-5f
#define QSCALE 1048576.0f           // 2^20 fixed-point scale for deterministic agg

// radix partition params (R8-proven)
#define BSH  8                      // 256 nodes per bucket
#define NBKT 196                    // ceil(50000/256)
#define BCAP 6144                   // per-bucket edge capacity (mean 5102)
#define EPB  4096                   // edges per pass-A block

struct alignas(16) SE8  { int   v[8];  };   // 4 {src,eid} pairs (fallback)
struct alignas(16) F16v { float f[16]; };   // one f32 attr row

// =====================  x -> fp16 side copy  =====================
__global__ __launch_bounds__(256) void xhalf_kernel(
    const float* __restrict__ x, __half* __restrict__ xh)
{
    const int i = blockIdx.x * 256 + threadIdx.x;
    if (i >= NN * D / 4) return;
    const float4 a = reinterpret_cast<const float4*>(x)[i];
    ushort4 h;
    h.x = __half_as_ushort(__float2half(a.x));
    h.y = __half_as_ushort(__float2half(a.y));
    h.z = __half_as_ushort(__float2half(a.z));
    h.w = __half_as_ushort(__float2half(a.w));
    reinterpret_cast<ushort4*>(xh)[i] = h;
}

// ============ pass A: LDS radix partition of edges into 196 buckets ==========
// (R8-verified)
__global__ __launch_bounds__(256) void partA_kernel(
    const int*  __restrict__ ei32,
    int*        __restrict__ gcur,      // [NBKT], zeroed
    uint2*      __restrict__ bucketed)  // [NBKT * BCAP]
{
    __shared__ uint2 s_staged[EPB];                       // 32 KB
    __shared__ int s_cnt[NBKT], s_pref[NBKT], s_cnt2[NBKT], s_gbase[NBKT];

    const int tid = threadIdx.x;
    const long long base = (long long)blockIdx.x * EPB;
    const int nedge = (int)((NE - base < EPB) ? (NE - base) : EPB);

    const int hi = ei32[2 * (tid & 63) + 1];
    const bool is64 = !__any(hi != 0);

    for (int i = tid; i < NBKT; i += 256) { s_cnt[i] = 0; s_cnt2[i] = 0; }
    __syncthreads();

    int srcv[16], dstv[16];
    #pragma unroll
    for (int i = 0; i < 16; ++i) {
        const int k = i * 256 + tid;
        int s = 0, d = 0;
        if (k < nedge) {
            const long long e = base + k;
            s = is64 ? ei32[2 * e]        : ei32[e];
            d = is64 ? ei32[2 * (NE + e)] : ei32[NE + e];
            atomicAdd(&s_cnt[d >> BSH], 1);
        }
        srcv[i] = s; dstv[i] = d;
    }
    __syncthreads();

    if (tid < NBKT) s_pref[tid] = s_cnt[tid];
    __syncthreads();
    for (int off = 1; off < NBKT; off <<= 1) {
        int v = 0;
        if (tid < NBKT && tid >= off) v = s_pref[tid - off];
        __syncthreads();
        if (tid < NBKT) s_pref[tid] += v;
        __syncthreads();
    }
    if (tid < NBKT) s_gbase[tid] = atomicAdd(&gcur[tid], s_cnt[tid]);
    __syncthreads();

    #pragma unroll
    for (int i = 0; i < 16; ++i) {
        const int k = i * 256 + tid;
        if (k < nedge) {
            const int d = dstv[i], b = d >> BSH;
            const int r = atomicAdd(&s_cnt2[b], 1);
            const int p = (s_pref[b] - s_cnt[b]) + r;     // excl prefix + rank
            s_staged[p] = make_uint2((unsigned)srcv[i] | ((unsigned)d << 16),
                                     (unsigned)(base + k));
        }
    }
    __syncthreads();

    for (int p = tid; p < nedge; p += 256) {
        const uint2 rec = s_staged[p];
        const int d = (int)(rec.x >> 16), b = d >> BSH;
        const int local = p - (s_pref[b] - s_cnt[b]);
        const int gpos = s_gbase[b] + local;
        if (gpos < BCAP)
            bucketed[(size_t)b * BCAP + gpos] = rec;
    }
}

// ===== pass B: per-bucket slot assignment (LDS cursors) + padded emit =======
// (R8-verified)
__global__ __launch_bounds__(512) void partB_kernel(
    const uint2* __restrict__ bucketed,
    const int*   __restrict__ gcur,
    int*         __restrict__ cursor,   // [NN] out: degrees
    int2*        __restrict__ padded)
{
    __shared__ int s_deg[1 << BSH];
    const int tid = threadIdx.x;
    const int b = blockIdx.x;

    for (int i = tid; i < (1 << BSH); i += 512) s_deg[i] = 0;
    __syncthreads();

    const int cnt = min(gcur[b], BCAP);
    const uint2* reg = bucketed + (size_t)b * BCAP;
    for (int k = tid; k < cnt; k += 512) {
        const uint2 rec = reg[k];
        const int src = (int)(rec.x & 0xffffu);
        const int dst = (int)(rec.x >> 16);
        const int slot = atomicAdd(&s_deg[dst & ((1 << BSH) - 1)], 1);
        if (slot < CAP)
            padded[(size_t)dst * CAP + slot] = make_int2(src, (int)rec.y);
    }
    __syncthreads();
    for (int i = tid; i < (1 << BSH); i += 512) {
        const int n = (b << BSH) + i;
        if (n < NN) cursor[n] = s_deg[i];
    }
}

// ==== gather4: R5's scalar-pipe f32 attrs + R9's depth-2 pipeline (2-edge groups) ====
__global__ __launch_bounds__(256) void gather4_kernel(
    const int2*   __restrict__ padded,
    const int*    __restrict__ cursor,
    const __half* __restrict__ xh,
    const float*  __restrict__ ea,
    const float*  __restrict__ W_edge,
    const float*  __restrict__ b_edge,
    float*        __restrict__ agg)
{
    const int tid  = threadIdx.x;
    const int lane = tid & 63;
    const int n = __builtin_amdgcn_readfirstlane(blockIdx.x * 4 + (tid >> 6));
    if (n >= NN) return;

    // lane's W_edge row in VGPRs (f32)
    float wv[ED];
    #pragma unroll
    for (int i = 0; i < ED / 4; ++i) {
        float4 t = reinterpret_cast<const float4*>(W_edge)[lane * (ED / 4) + i];
        wv[4*i+0] = t.x; wv[4*i+1] = t.y; wv[4*i+2] = t.z; wv[4*i+3] = t.w;
    }
    const float bo = b_edge[lane];

    const int deg = __builtin_amdgcn_readfirstlane(min(cursor[n], CAP));
    const int2* row = padded + (size_t)n * CAP;
    if (deg <= 0) { agg[(size_t)n * D + lane] = 0.f; return; }

    const int G = (deg + 1) >> 1;   // 2-edge groups

    auto LD_SE = [&](int g) -> int4 {
        return *reinterpret_cast<const int4*>(row + g * 2);  // 2 int2 pairs
    };
    auto LD_GRP = [&](const int4& s4, int g, F16v at[2], float xv[2], bool lv[2]) {
        #pragma unroll
        for (int j = 0; j < 2; ++j) {
            const int idx = g * 2 + j;
            const bool lj = idx < deg;                         // wave-uniform
            const int src = __builtin_amdgcn_readfirstlane(lj ? (j ? s4.z : s4.x) : s4.x);
            const int eid = __builtin_amdgcn_readfirstlane(lj ? (j ? s4.w : s4.y) : s4.y);
            at[j] = *reinterpret_cast<const F16v*>(ea + (size_t)eid * ED);  // SMEM x16
            xv[j] = __half2float(xh[(size_t)src * D + lane]);
            lv[j] = lj;
        }
    };
    auto COMP = [&](const F16v at[2], const float xv[2], const bool lv[2], int& iacc) {
        #pragma unroll
        for (int j = 0; j < 2; ++j) {
            if (lv[j]) {                                       // wave-uniform
                float d = bo;
                #pragma unroll
                for (int k = 0; k < ED; ++k) d += at[j].f[k] * wv[k];
                iacc += __float2int_rn(fmaxf(d + xv[j], 0.f) * QSCALE);
            }
        }
    };

    int iacc = 0;
    F16v atA[2], atB[2];
    float xvA[2], xvB[2];
    bool lvA[2], lvB[2];
    int4 sB = LD_SE(0);
    LD_GRP(sB, 0, atA, xvA, lvA);
    if (G > 1) sB = LD_SE(1);

    for (int g = 0; g < G; g += 2) {
        if (g + 1 < G) LD_GRP(sB, g + 1, atB, xvB, lvB);
        if (g + 2 < G) sB = LD_SE(g + 2);
        COMP(atA, xvA, lvA, iacc);
        if (g + 2 < G) LD_GRP(sB, g + 2, atA, xvA, lvA);
        if (g + 3 < G) sB = LD_SE(g + 3);
        if (g + 1 < G) COMP(atB, xvB, lvB, iacc);
    }
    agg[(size_t)n * D + lane] = (float)iacc * (1.0f / QSCALE);
}

// ============== fallback scatter (global atomic slot assignment) =============
__global__ __launch_bounds__(256) void scatter_kernel(
    const int* __restrict__ ei32,
    int*       __restrict__ cursor,
    int2*      __restrict__ padded)
{
    const int e = blockIdx.x * 256 + threadIdx.x;
    const int hi = ei32[2 * (threadIdx.x & 63) + 1];
    const bool is64 = !__any(hi != 0);
    if (e >= NE) return;
    const int src = is64 ? ei32[2 * e]        : ei32[e];
    const int dst = is64 ? ei32[2 * (NE + e)] : ei32[NE + e];
    const int slot = atomicAdd(&cursor[dst], 1);
    if (slot < CAP) padded[(size_t)dst * CAP + slot] = make_int2(src, e);
}

// =============== fallback gather (R8): scalar-pipe f32 attrs, no pipeline ====
template<bool XH>
__global__ __launch_bounds__(256) void gather_kernel(
    const int2*  __restrict__ padded,
    const int*   __restrict__ cursor,
    const float* __restrict__ x,
    const __half* __restrict__ xh,
    const float* __restrict__ ea,
    const float* __restrict__ W_edge,
    const float* __restrict__ b_edge,
    float*       __restrict__ agg)
{
    const int tid  = threadIdx.x;
    const int lane = tid & 63;
    const int n = __builtin_amdgcn_readfirstlane(blockIdx.x * 4 + (tid >> 6));
    if (n >= NN) return;

    float wv[ED];
    #pragma unroll
    for (int i = 0; i < ED / 4; ++i) {
        float4 t = reinterpret_cast<const float4*>(W_edge)[lane * (ED / 4) + i];
        wv[4*i+0] = t.x; wv[4*i+1] = t.y; wv[4*i+2] = t.z; wv[4*i+3] = t.w;
    }
    const float bo = b_edge[lane];

    const int deg = __builtin_amdgcn_readfirstlane(min(cursor[n], CAP));
    const int2* row = padded + (size_t)n * CAP;

    int iacc = 0;
    for (int e0 = 0; e0 < deg; e0 += 4) {
        const SE8 g = *reinterpret_cast<const SE8*>(row + e0);
        const bool l1 = (e0 + 1 < deg), l2 = (e0 + 2 < deg), l3 = (e0 + 3 < deg);
        const int src0 = __builtin_amdgcn_readfirstlane(g.v[0]);
        const int eid0 = __builtin_amdgcn_readfirstlane(g.v[1]);
        const int src1 = __builtin_amdgcn_readfirstlane(l1 ? g.v[2] : g.v[0]);
        const int eid1 = __builtin_amdgcn_readfirstlane(l1 ? g.v[3] : g.v[1]);
        const int src2 = __builtin_amdgcn_readfirstlane(l2 ? g.v[4] : g.v[0]);
        const int eid2 = __builtin_amdgcn_readfirstlane(l2 ? g.v[5] : g.v[1]);
        const int src3 = __builtin_amdgcn_readfirstlane(l3 ? g.v[6] : g.v[0]);
        const int eid3 = __builtin_amdgcn_readfirstlane(l3 ? g.v[7] : g.v[1]);

        const F16v a0 = *reinterpret_cast<const F16v*>(ea + (size_t)eid0 * ED);
        const F16v a1 = *reinterpret_cast<const F16v*>(ea + (size_t)eid1 * ED);
        const F16v a2 = *reinterpret_cast<const F16v*>(ea + (size_t)eid2 * ED);
        const F16v a3 = *reinterpret_cast<const F16v*>(ea + (size_t)eid3 * ED);

        float xv0, xv1, xv2, xv3;
        if (XH) {
            xv0 = __half2float(xh[(size_t)src0 * D + lane]);
            xv1 = __half2float(xh[(size_t)src1 * D + lane]);
            xv2 = __half2float(xh[(size_t)src2 * D + lane]);
            xv3 = __half2float(xh[(size_t)src3 * D + lane]);
        } else {
            xv0 = x[(size_t)src0 * D + lane];
            xv1 = x[(size_t)src1 * D + lane];
            xv2 = x[(size_t)src2 * D + lane];
            xv3 = x[(size_t)src3 * D + lane];
        }

        float d0 = bo, d1 = bo, d2 = bo, d3 = bo;
        #pragma unroll
        for (int k = 0; k < ED; ++k) {
            d0 += a0.f[k] * wv[k];
            d1 += a1.f[k] * wv[k];
            d2 += a2.f[k] * wv[k];
            d3 += a3.f[k] * wv[k];
        }
        iacc += __float2int_rn(fmaxf(d0 + xv0, 0.f) * QSCALE);
        iacc += l1 ? __float2int_rn(fmaxf(d1 + xv1, 0.f) * QSCALE) : 0;
        iacc += l2 ? __float2int_rn(fmaxf(d2 + xv2, 0.f) * QSCALE) : 0;
        iacc += l3 ? __float2int_rn(fmaxf(d3 + xv3, 0.f) * QSCALE) : 0;
    }
    agg[(size_t)n * D + lane] = (float)iacc * (1.0f / QSCALE);
}

// =====================  path B fallback: atomic edge kernel  =================
__global__ __launch_bounds__(256) void edge_kernel(
    const float* __restrict__ x,
    const int*   __restrict__ ei32,
    const float* __restrict__ ea,
    const float* __restrict__ W_edge,
    const float* __restrict__ b_edge,
    float*       __restrict__ agg)
{
    __shared__ float s_ea[64 * ED];
    __shared__ int   s_src[64];
    __shared__ int   s_dst[64];

    const int tid  = threadIdx.x;
    const int lane = tid & 63;
    const int wave = tid >> 6;
    const long long ebase = (long long)blockIdx.x * 64;

    const int hi = ei32[2 * lane + 1];
    const bool is64 = !__any(hi != 0);

    float w[ED];
    #pragma unroll
    for (int i = 0; i < ED / 4; ++i) {
        float4 t = reinterpret_cast<const float4*>(W_edge)[lane * (ED / 4) + i];
        w[4*i+0] = t.x; w[4*i+1] = t.y; w[4*i+2] = t.z; w[4*i+3] = t.w;
    }
    const float bo = b_edge[lane];

    reinterpret_cast<float4*>(s_ea)[tid] =
        reinterpret_cast<const float4*>(ea + ebase * ED)[tid];

    if (tid < 64) {
        long long e = ebase + tid;
        s_src[tid] = is64 ? ei32[2 * e] : ei32[e];
    } else if (tid < 128) {
        long long e = ebase + (tid - 64);
        s_dst[tid - 64] = is64 ? ei32[2 * (NE + e)] : ei32[NE + e];
    }
    __syncthreads();

    #pragma unroll 4
    for (int i = 0; i < 16; ++i) {
        const int el = wave * 16 + i;
        float acc = bo;
        const float* er = s_ea + el * ED;
        #pragma unroll
        for (int k = 0; k < ED; ++k) acc += er[k] * w[k];
        const long long s = s_src[el];
        const long long d = s_dst[el];
        float m = fmaxf(acc + x[s * D + lane], 0.f);
        atomicAdd(&agg[d * D + lane], m);
    }
}

// =====================  node stages  =====================

__global__ __launch_bounds__(256) void node1_kernel(
    const float* __restrict__ x,
    const float* __restrict__ agg,
    const float* __restrict__ W1,
    const float* __restrict__ b1,
    float*       __restrict__ h1,
    float*       __restrict__ colsum,
    float*       __restrict__ colsumsq)
{
    __shared__ float s_h[64 * D];
    const int tid  = threadIdx.x;
    const int o    = tid & 63;
    const int wave = tid >> 6;
    const long long rbase = (long long)blockIdx.x * 64;

    float w[D];
    #pragma unroll
    for (int i = 0; i < D / 4; ++i) {
        float4 t = reinterpret_cast<const float4*>(W1)[o * (D / 4) + i];
        w[4*i+0] = t.x; w[4*i+1] = t.y; w[4*i+2] = t.z; w[4*i+3] = t.w;
    }

    #pragma unroll
    for (int i = 0; i < 4; ++i) {
        const int f4 = tid + 256 * i;
        const long long row = rbase + (f4 >> 4);
        float4 t = make_float4(0.f, 0.f, 0.f, 0.f);
        if (row < NN) {
            float4 a = reinterpret_cast<const float4*>(x)  [row * (D/4) + (f4 & 15)];
            float4 g = reinterpret_cast<const float4*>(agg)[row * (D/4) + (f4 & 15)];
            t.x = a.x + g.x; t.y = a.y + g.y; t.z = a.z + g.z; t.w = a.w + g.w;
        }
        reinterpret_cast<float4*>(s_h)[f4] = t;
    }
    __syncthreads();

    const float bb = b1[o];
    float psum = 0.f, psq = 0.f;
    for (int i = 0; i < 16; ++i) {
        const int r = wave + 4 * i;
        const long long row = rbase + r;
        float acc = bb;
        const float4* sr = reinterpret_cast<const float4*>(s_h + r * D);
        #pragma unroll
        for (int k = 0; k < D / 4; ++k) {
            float4 v = sr[k];
            acc += v.x * w[4*k+0] + v.y * w[4*k+1] + v.z * w[4*k+2] + v.w * w[4*k+3];
        }
        if (row < NN) {
            h1[row * D + o] = acc;
            psum += acc;
            psq  += acc * acc;
        }
    }
    __syncthreads();
    s_h[wave * 64 + o]       = psum;
    s_h[256 + wave * 64 + o] = psq;
    __syncthreads();
    if (tid < 64) {
        float s0 = s_h[tid] + s_h[64 + tid] + s_h[128 + tid] + s_h[192 + tid];
        float q0 = s_h[256 + tid] + s_h[320 + tid] + s_h[384 + tid] + s_h[448 + tid];
        atomicAdd(&colsum[tid], s0);
        atomicAdd(&colsumsq[tid], q0);
    }
}

__global__ void bnstats_kernel(
    const float* __restrict__ colsum,
    const float* __restrict__ colsumsq,
    const float* __restrict__ gamma,
    const float* __restrict__ beta,
    float*       __restrict__ scale,
    float*       __restrict__ shift)
{
    const int o = threadIdx.x;
    const float inv_n = 1.f / (float)NN;
    const float mean = colsum[o] * inv_n;
    const float var  = colsumsq[o] * inv_n - mean * mean;
    const float sc   = gamma[o] * rsqrtf(var + BN_EPS);
    scale[o] = sc;
    shift[o] = beta[o] - mean * sc;
}

__global__ __launch_bounds__(256) void node2_kernel(
    const float* __restrict__ h1,
    const float* __restrict__ scale,
    const float* __restrict__ shift,
    const float* __restrict__ W2,
    const float* __restrict__ b2,
    float*       __restrict__ out)
{
    __shared__ float s_a[64 * D];
    __shared__ float s_sc[D];
    __shared__ float s_sh[D];
    const int tid  = threadIdx.x;
    const int o    = tid & 63;
    const int wave = tid >> 6;
    const long long rbase = (long long)blockIdx.x * 64;

    if (tid < D) { s_sc[tid] = scale[tid]; s_sh[tid] = shift[tid]; }

    float w[D];
    #pragma unroll
    for (int i = 0; i < D / 4; ++i) {
        float4 t = reinterpret_cast<const float4*>(W2)[o * (D / 4) + i];
        w[4*i+0] = t.x; w[4*i+1] = t.y; w[4*i+2] = t.z; w[4*i+3] = t.w;
    }
    __syncthreads();

    #pragma unroll
    for (int i = 0; i < 4; ++i) {
        const int f4 = tid + 256 * i;
        const long long row = rbase + (f4 >> 4);
        float4 t = make_float4(0.f, 0.f, 0.f, 0.f);
        if (row < NN) {
            float4 v = reinterpret_cast<const float4*>(h1)[row * (D/4) + (f4 & 15)];
            const int c = (f4 & 15) * 4;
            t.x = fmaxf(v.x * s_sc[c+0] + s_sh[c+0], 0.f);
            t.y = fmaxf(v.y * s_sc[c+1] + s_sh[c+1], 0.f);
            t.z = fmaxf(v.z * s_sc[c+2] + s_sh[c+2], 0.f);
            t.w = fmaxf(v.w * s_sc[c+3] + s_sh[c+3], 0.f);
        }
        reinterpret_cast<float4*>(s_a)[f4] = t;
    }
    __syncthreads();

    const float bb = b2[o];
    for (int i = 0; i < 16; ++i) {
        const int r = wave + 4 * i;
        const long long row = rbase + r;
        float acc = bb;
        const float4* sr = reinterpret_cast<const float4*>(s_a + r * D);
        #pragma unroll
        for (int k = 0; k < D / 4; ++k) {
            float4 v = sr[k];
            acc += v.x * w[4*k+0] + v.y * w[4*k+1] + v.z * w[4*k+2] + v.w * w[4*k+3];
        }
        if (row < NN) out[row * D + o] = acc;
    }
}

// =====================  launch  =====================

extern "C" void kernel_launch(void* const* d_in, const int* in_sizes, int n_in,
                              void* d_out, int out_size, void* d_ws, size_t ws_size,
                              hipStream_t stream)
{
    const float* x      = (const float*)d_in[0];
    const int*   ei32   = (const int*)  d_in[1];
    const float* ea     = (const float*)d_in[2];
    const float* W_edge = (const float*)d_in[3];
    const float* b_edge = (const float*)d_in[4];
    const float* W1     = (const float*)d_in[5];
    const float* b1     = (const float*)d_in[6];
    const float* gamma  = (const float*)d_in[7];
    const float* beta   = (const float*)d_in[8];
    const float* W2     = (const float*)d_in[9];
    const float* b2     = (const float*)d_in[10];
    float* out = (float*)d_out;

    // layout: agg | h1 | cursor | colsum..(256f) | padded | xh | gcur
    float*  agg      = (float*)d_ws;                        // NN*D f32
    float*  h1       = agg + (size_t)NN * D;                // NN*D f32
    int*    cursor   = (int*)(h1 + (size_t)NN * D);         // NN int
    float*  colsum   = (float*)(cursor + NN);               // 64
    float*  colsumsq = colsum + 64;                         // 64
    float*  scale    = colsumsq + 64;                       // 64
    float*  shift    = scale + 64;                          // 64
    int2*   padded   = (int2*)(shift + 64);                 // NN*CAP int2 (16B-aligned)
    __half* xh       = (__half*)(padded + (size_t)NN * CAP);// NN*D halves
    int*    gcur     = (int*)(xh + (size_t)NN * D);         // NBKT
    uint2*  bucketed = (uint2*)h1;                          // aliases h1 (dead until node1)

    const size_t need_base = (size_t)(2 * NN * D + NN + 256) * 4 + (size_t)NN * CAP * 8;
    const size_t need_t2   = need_base + (size_t)NN * D * 2;
    const size_t need_t1   = need_t2 + (size_t)NBKT * 4;

    if (ws_size >= need_t1) {
        hipMemsetAsync(gcur, 0, (size_t)NBKT * 4, stream);
        hipMemsetAsync(colsum, 0, 256 * 4, stream);         // BN accums every call
        xhalf_kernel<<<(NN * D / 4 + 255) / 256, 256, 0, stream>>>(x, xh);
        partA_kernel<<<(NE + EPB - 1) / EPB, 256, 0, stream>>>(ei32, gcur, bucketed);
        partB_kernel<<<NBKT, 512, 0, stream>>>(bucketed, gcur, cursor, padded);
        gather4_kernel<<<(NN + 3) / 4, 256, 0, stream>>>(padded, cursor, xh, ea, W_edge, b_edge, agg);
        node1_kernel<<<(NN + 63) / 64, 256, 0, stream>>>(x, agg, W1, b1, h1, colsum, colsumsq);
        bnstats_kernel<<<1, 64, 0, stream>>>(colsum, colsumsq, gamma, beta, scale, shift);
        node2_kernel<<<(NN + 63) / 64, 256, 0, stream>>>(h1, scale, shift, W2, b2, out);
        return;
    }

    if (ws_size >= need_t2) {
        hipMemsetAsync(cursor, 0, (size_t)(NN + 256) * 4, stream);
        xhalf_kernel<<<(NN * D / 4 + 255) / 256, 256, 0, stream>>>(x, xh);
        scatter_kernel<<<(NE + 255) / 256, 256, 0, stream>>>(ei32, cursor, padded);
        gather_kernel<true><<<(NN + 3) / 4, 256, 0, stream>>>(padded, cursor, x, xh, ea, W_edge, b_edge, agg);
    } else if (ws_size >= need_base) {
        hipMemsetAsync(cursor, 0, (size_t)(NN + 256) * 4, stream);
        scatter_kernel<<<(NE + 255) / 256, 256, 0, stream>>>(ei32, cursor, padded);
        gather_kernel<false><<<(NN + 3) / 4, 256, 0, stream>>>(padded, cursor, x, xh, ea, W_edge, b_edge, agg);
    } else {
        hipMemsetAsync(agg, 0, (size_t)NN * D * 4, stream);
        hipMemsetAsync(cursor, 0, (size_t)(NN + 256) * 4, stream);
        edge_kernel<<<NE / 64, 256, 0, stream>>>(x, ei32, ea, W_edge, b_edge, agg);
    }
    node1_kernel<<<(NN + 63) / 64, 256, 0, stream>>>(x, agg, W1, b1, h1, colsum, colsumsq);
    bnstats_kernel<<<1, 64, 0, stream>>>(colsum, colsumsq, gamma, beta, scale, shift);
    node2_kernel<<<(NN + 63) / 64, 256, 0, stream>>>(h1, scale, shift, W2, b2, out);
}